// Round 1
// baseline (1282.641 us; speedup 1.0000x reference)
//
#include <hip/hip_runtime.h>
#include <math.h>

constexpr int NNODES  = 16384;
constexpr int NEDGES  = 131072;
constexpr int NGRAPHS = 16;

__device__ __forceinline__ float leaky(float x, float s){ return x >= 0.0f ? x : s * x; }

// ---------------- CSR build (edges fixed across layers; build once) ----------------
__global__ void k_deg(const int* __restrict__ dst, int* __restrict__ deg){
  int e = blockIdx.x * 256 + threadIdx.x;
  if (e < NEDGES) atomicAdd(&deg[dst[e]], 1);
}

__global__ __launch_bounds__(1024) void k_scan(const int* __restrict__ deg,
                                               int* __restrict__ rowptr,
                                               int* __restrict__ cursor){
  __shared__ int sums[1024];
  int t = threadIdx.x;
  int loc[16];
  int s = 0;
  #pragma unroll
  for (int i = 0; i < 16; i++){ loc[i] = deg[t*16 + i]; s += loc[i]; }
  sums[t] = s; __syncthreads();
  for (int off = 1; off < 1024; off <<= 1){
    int v = (t >= off) ? sums[t - off] : 0;
    __syncthreads();
    sums[t] += v;
    __syncthreads();
  }
  int base = (t > 0) ? sums[t-1] : 0;
  #pragma unroll
  for (int i = 0; i < 16; i++){
    rowptr[t*16 + i] = base; cursor[t*16 + i] = base; base += loc[i];
  }
  if (t == 1023) rowptr[NNODES] = base;
}

__global__ void k_scatter(const int* __restrict__ src, const int* __restrict__ dst,
                          int* __restrict__ cursor, int* __restrict__ perm){
  int e = blockIdx.x * 256 + threadIdx.x;
  if (e < NEDGES){ int p = atomicAdd(&cursor[dst[e]], 1); perm[p] = src[e]; }
}

__global__ void k_counts(const int* __restrict__ gid, float* __restrict__ counts){
  int n = blockIdx.x * 256 + threadIdx.x;
  if (n < NNODES) atomicAdd(&counts[gid[n]], 1.0f);
}

// ---------------- fp32 GEMM: C[M,NN] = X[M,K] @ W[K,NN], 64x64 tile, BK=16 ----------------
__global__ __launch_bounds__(256) void k_gemm(const float* __restrict__ X,
                                              const float* __restrict__ W,
                                              float* __restrict__ C, int K, int NN){
  __shared__ float Xs[16][64];   // [k][row]
  __shared__ float Ws[16][64];   // [k][col]
  int t  = threadIdx.x;
  int tx = t & 15, ty = t >> 4;
  int bx = blockIdx.x, by = blockIdx.y;
  float acc[4][4] = {};
  int rowx = t >> 2;          // 0..63
  int kkx  = (t & 3) << 2;    // 0,4,8,12
  int kw   = t >> 4;          // 0..15
  int colw = (t & 15) << 2;   // 0..60
  const float* Xp = X + (size_t)(by*64 + rowx) * K + kkx;
  const float* Wp = W + (size_t)kw * NN + bx*64 + colw;
  for (int k0 = 0; k0 < K; k0 += 16){
    float4 xa = *(const float4*)(Xp + k0);
    float4 wa = *(const float4*)(Wp + (size_t)k0 * NN);
    __syncthreads();
    Xs[kkx+0][rowx] = xa.x; Xs[kkx+1][rowx] = xa.y; Xs[kkx+2][rowx] = xa.z; Xs[kkx+3][rowx] = xa.w;
    *(float4*)&Ws[kw][colw] = wa;
    __syncthreads();
    #pragma unroll
    for (int k = 0; k < 16; k++){
      float4 a = *(const float4*)&Xs[k][ty << 2];
      float4 b = *(const float4*)&Ws[k][tx << 2];
      acc[0][0]+=a.x*b.x; acc[0][1]+=a.x*b.y; acc[0][2]+=a.x*b.z; acc[0][3]+=a.x*b.w;
      acc[1][0]+=a.y*b.x; acc[1][1]+=a.y*b.y; acc[1][2]+=a.y*b.z; acc[1][3]+=a.y*b.w;
      acc[2][0]+=a.z*b.x; acc[2][1]+=a.z*b.y; acc[2][2]+=a.z*b.z; acc[2][3]+=a.z*b.w;
      acc[3][0]+=a.w*b.x; acc[3][1]+=a.w*b.y; acc[3][2]+=a.w*b.z; acc[3][3]+=a.w*b.w;
    }
  }
  float* Cp = C + (size_t)(by*64 + (ty << 2)) * NN + bx*64 + (tx << 2);
  #pragma unroll
  for (int i = 0; i < 4; i++){
    float4 v = make_float4(acc[i][0], acc[i][1], acc[i][2], acc[i][3]);
    *(float4*)(Cp + (size_t)i * NN) = v;
  }
}

// ---------------- el/er: per (node,head) dot of h-row with attn vectors ----------------
template<int D>
__global__ __launch_bounds__(256) void k_elr(const float* __restrict__ HB,
                                             const float* __restrict__ al,
                                             const float* __restrict__ ar,
                                             float* __restrict__ el, float* __restrict__ er){
  int wid = threadIdx.x >> 6, lane = threadIdx.x & 63;
  int row = blockIdx.x * 4 + wid;          // row in [0, 2N)
  const float* hrow = HB + (size_t)(row >> 1) * (2*D) + (row & 1) * D;
  const float* alp  = al + (row & 1) * D;
  const float* arp  = ar + (row & 1) * D;
  float sl = 0.0f, sr = 0.0f;
  #pragma unroll
  for (int j = 0; j < D/64; j++){
    int c = lane + j*64;
    float v = hrow[c];
    sl += v * alp[c]; sr += v * arp[c];
  }
  for (int o = 32; o; o >>= 1){ sl += __shfl_xor(sl, o); sr += __shfl_xor(sr, o); }
  if (lane == 0){ el[row] = sl; er[row] = sr; }
}

// ---------------- attention: one wave per destination node; out = attn + residual ----------------
template<int D>
__global__ __launch_bounds__(256) void k_attn(const float* __restrict__ HB,
                                              float* __restrict__ RB,
                                              const float* __restrict__ el,
                                              const float* __restrict__ er,
                                              const int* __restrict__ rowptr,
                                              const int* __restrict__ perm){
  constexpr int CPT = (2*D)/64;
  int wid = threadIdx.x >> 6, lane = threadIdx.x & 63;
  int n = blockIdx.x * 4 + wid;
  int r0 = rowptr[n], r1 = rowptr[n+1];
  if (r0 == r1) return;   // no in-edges: output = residual already in RB
  float er0 = er[n*2], er1 = er[n*2+1];
  float mx0 = -1e30f, mx1 = -1e30f;
  for (int e = r0 + lane; e < r1; e += 64){
    int s = perm[e];
    mx0 = fmaxf(mx0, leaky(el[s*2]   + er0, 0.2f));
    mx1 = fmaxf(mx1, leaky(el[s*2+1] + er1, 0.2f));
  }
  for (int o = 32; o; o >>= 1){ mx0 = fmaxf(mx0, __shfl_xor(mx0, o)); mx1 = fmaxf(mx1, __shfl_xor(mx1, o)); }
  float sm0 = 0.0f, sm1 = 0.0f;
  for (int e = r0 + lane; e < r1; e += 64){
    int s = perm[e];
    sm0 += expf(leaky(el[s*2]   + er0, 0.2f) - mx0);
    sm1 += expf(leaky(el[s*2+1] + er1, 0.2f) - mx1);
  }
  for (int o = 32; o; o >>= 1){ sm0 += __shfl_xor(sm0, o); sm1 += __shfl_xor(sm1, o); }
  float inv0 = 1.0f / sm0, inv1 = 1.0f / sm1;
  float acc[CPT];
  #pragma unroll
  for (int j = 0; j < CPT; j++) acc[j] = 0.0f;
  for (int e = r0; e < r1; ++e){
    int s = perm[e];
    float a0 = expf(leaky(el[s*2]   + er0, 0.2f) - mx0) * inv0;
    float a1 = expf(leaky(el[s*2+1] + er1, 0.2f) - mx1) * inv1;
    const float* hrow = HB + (size_t)s * (2*D);
    #pragma unroll
    for (int j = 0; j < CPT; j++){
      int c = lane + j*64;
      acc[j] += (c < D ? a0 : a1) * hrow[c];
    }
  }
  float* rrow = RB + (size_t)n * (2*D);
  #pragma unroll
  for (int j = 0; j < CPT; j++){
    int c = lane + j*64;
    rrow[c] += acc[j];
  }
}

// ---------------- GraphNorm stats: per-column sums over nodes (columns = 2d) ----------------
__global__ __launch_bounds__(256) void k_stats(const float* __restrict__ R, int nn,
                                               float* __restrict__ gsum, float* __restrict__ gsq){
  __shared__ float rs[256], rq[256];
  int t = threadIdx.x, lane = t & 63, w = t >> 6;
  int nodeb = blockIdx.x * 256;
  for (int ch = 0; ch < nn; ch += 64){
    int col = ch + lane;
    float s = 0.0f, q = 0.0f;
    const float* base = R + (size_t)(nodeb + w*64) * nn + col;
    for (int i = 0; i < 64; i++){ float v = base[(size_t)i * nn]; s += v; q += v*v; }
    rs[t] = s; rq[t] = q; __syncthreads();
    if (t < 64){
      float ss = rs[t] + rs[t+64] + rs[t+128] + rs[t+192];
      float qq = rq[t] + rq[t+64] + rq[t+128] + rq[t+192];
      atomicAdd(&gsum[ch + t], ss);
      atomicAdd(&gsq [ch + t], qq);
    }
    __syncthreads();
  }
}

__global__ void k_finstats(const float* __restrict__ gsum, const float* __restrict__ gsq,
                           const float* __restrict__ alpha,
                           float* __restrict__ mean, float* __restrict__ rstd, int d){
  int t = threadIdx.x;
  if (t >= d) return;
  float s = gsum[t] + gsum[t + d];
  float q = gsq[t]  + gsq[t + d];
  const float M = (float)(2 * NNODES);
  float m   = s / M;
  float msq = q / M;
  float a   = alpha[t];
  float var = msq - a * m * m * (2.0f - a);   // E[(x-am)^2] = E[x^2] - a m^2 (2-a)
  mean[t] = m;
  rstd[t] = rsqrtf(var + 1e-5f);
}

// ---------------- norm apply + leaky + head-mean + graph pooling (fused) ----------------
__global__ __launch_bounds__(256) void k_norm_pool(const float* __restrict__ R,
                                                   float* __restrict__ Xn,   // next-layer input (or null)
                                                   const float* __restrict__ mean,
                                                   const float* __restrict__ rstd,
                                                   const float* __restrict__ gamma,
                                                   const float* __restrict__ beta,
                                                   const float* __restrict__ alpha,
                                                   float* __restrict__ pool, int d, int loff){
  int t = threadIdx.x, lane = t & 63, w = t >> 6;
  int c = blockIdx.y * 64 + lane;
  int nodeb = blockIdx.x * 256 + w * 64;
  int g = blockIdx.x >> 2;                 // 4 node-blocks per graph (1024 nodes/graph)
  float m  = mean[c], rs = rstd[c], ga = gamma[c], be = beta[c];
  float am = alpha[c] * m;
  int nn = 2 * d;
  const float* r0 = R + (size_t)nodeb * nn + c;
  float accp = 0.0f;
  for (int i = 0; i < 64; i++){
    float v0 = r0[(size_t)i * nn];
    float v1 = r0[(size_t)i * nn + d];
    float y0 = ga * (v0 - am) * rs + be; y0 = y0 >= 0.0f ? y0 : 0.01f * y0;
    float y1 = ga * (v1 - am) * rs + be; y1 = y1 >= 0.0f ? y1 : 0.01f * y1;
    if (Xn){
      Xn[(size_t)(nodeb + i) * nn + c]     = y0;
      Xn[(size_t)(nodeb + i) * nn + d + c] = y1;
    }
    accp += y0 + y1;
  }
  accp *= 0.5f;
  __shared__ float red[256];
  red[t] = accp; __syncthreads();
  if (t < 64){
    float s = red[t] + red[t+64] + red[t+128] + red[t+192];
    atomicAdd(&pool[g * 896 + loff + blockIdx.y * 64 + t], s);
  }
}

__global__ void k_final(const float* __restrict__ pool, const float* __restrict__ counts,
                        float* __restrict__ out){
  int idx = blockIdx.x * 256 + threadIdx.x;
  if (idx >= NGRAPHS * 896) return;
  int g = idx / 896;
  float v = pool[idx] / counts[g];
  out[idx] = v >= 0.0f ? v : 0.01f * v;
}

// ---------------------------------------------------------------------------------------
extern "C" void kernel_launch(void* const* d_in, const int* in_sizes, int n_in,
                              void* d_out, int out_size, void* d_ws, size_t ws_size,
                              hipStream_t stream){
  const float* x0 = (const float*)d_in[0];
  const float *W[3], *AL[3], *AR[3], *RW[3], *GA[3], *BE[3], *ALP[3];
  for (int l = 0; l < 3; l++){
    const int b = 1 + l*7;
    W[l]  = (const float*)d_in[b+0];
    AL[l] = (const float*)d_in[b+1];
    AR[l] = (const float*)d_in[b+2];
    RW[l] = (const float*)d_in[b+3];
    GA[l] = (const float*)d_in[b+4];
    BE[l] = (const float*)d_in[b+5];
    ALP[l]= (const float*)d_in[b+6];
  }
  const int* esrc = (const int*)d_in[22];
  const int* edst = (const int*)d_in[23];
  const int* gid  = (const int*)d_in[24];
  float* out = (float*)d_out;

  char* p = (char*)d_ws;
  auto carve = [&](size_t bytes)->void*{
    void* r = (void*)p; p += (bytes + 255) & ~(size_t)255; return r;
  };
  float* HB     = (float*)carve((size_t)NNODES * 1024 * 4);  // h = x@W    [N, 2d] max 64MB
  float* RB     = (float*)carve((size_t)NNODES * 1024 * 4);  // r then out [N, 2d] max 64MB
  float* XA     = (float*)carve((size_t)NNODES * 256  * 4);  // y0 [N,256]
  float* XB     = (float*)carve((size_t)NNODES * 512  * 4);  // y1 [N,512]
  float* el     = (float*)carve((size_t)NNODES * 2 * 4);
  float* er     = (float*)carve((size_t)NNODES * 2 * 4);
  int*   deg    = (int*)  carve((size_t)NNODES * 4);
  int*   rowptr = (int*)  carve((size_t)(NNODES + 1) * 4);
  int*   cursor = (int*)  carve((size_t)NNODES * 4);
  int*   perm   = (int*)  carve((size_t)NEDGES * 4);
  float* stats  = (float*)carve(2048 * 4);                   // gsum[1024] | gsq[1024]
  float* meanb  = (float*)carve(512 * 4);
  float* rstdb  = (float*)carve(512 * 4);
  float* pool   = (float*)carve((size_t)NGRAPHS * 896 * 4);
  float* countsF= (float*)carve((size_t)NGRAPHS * 4);
  (void)ws_size; (void)in_sizes; (void)n_in; (void)out_size;

  hipMemsetAsync(deg, 0, NNODES * 4, stream);
  hipMemsetAsync(pool, 0, NGRAPHS * 896 * 4, stream);
  hipMemsetAsync(countsF, 0, NGRAPHS * 4, stream);

  k_deg    <<<NEDGES/256, 256, 0, stream>>>(edst, deg);
  k_scan   <<<1, 1024, 0, stream>>>(deg, rowptr, cursor);
  k_scatter<<<NEDGES/256, 256, 0, stream>>>(esrc, edst, cursor, perm);
  k_counts <<<NNODES/256, 256, 0, stream>>>(gid, countsF);

  const float* xin = x0;
  int loff = 0;
  const int dims[3] = {128, 256, 512};
  for (int l = 0; l < 3; l++){
    int d = dims[l], nn = 2*d;
    dim3 gg(nn/64, NNODES/64);
    k_gemm<<<gg, 256, 0, stream>>>(xin, W[l],  HB, d, nn);
    k_gemm<<<gg, 256, 0, stream>>>(xin, RW[l], RB, d, nn);
    if (d == 128){
      k_elr <128><<<NNODES*2/4, 256, 0, stream>>>(HB, AL[l], AR[l], el, er);
      k_attn<128><<<NNODES/4,   256, 0, stream>>>(HB, RB, el, er, rowptr, perm);
    } else if (d == 256){
      k_elr <256><<<NNODES*2/4, 256, 0, stream>>>(HB, AL[l], AR[l], el, er);
      k_attn<256><<<NNODES/4,   256, 0, stream>>>(HB, RB, el, er, rowptr, perm);
    } else {
      k_elr <512><<<NNODES*2/4, 256, 0, stream>>>(HB, AL[l], AR[l], el, er);
      k_attn<512><<<NNODES/4,   256, 0, stream>>>(HB, RB, el, er, rowptr, perm);
    }
    hipMemsetAsync(stats, 0, 2048 * 4, stream);
    k_stats   <<<NNODES/256, 256, 0, stream>>>(RB, nn, stats, stats + 1024);
    k_finstats<<<1, 512, 0, stream>>>(stats, stats + 1024, ALP[l], meanb, rstdb, d);
    float* xn = (l == 0) ? XA : (l == 1) ? XB : nullptr;
    dim3 gn(NNODES/256, d/64);
    k_norm_pool<<<gn, 256, 0, stream>>>(RB, xn, meanb, rstdb, GA[l], BE[l], ALP[l], pool, d, loff);
    xin = xn; loff += d;
  }
  k_final<<<(NGRAPHS*896 + 255)/256, 256, 0, stream>>>(pool, countsF, out);
}

// Round 2
// 719.407 us; speedup vs baseline: 1.7829x; 1.7829x over previous
//
#include <hip/hip_runtime.h>
#include <math.h>

constexpr int NNODES  = 16384;
constexpr int NEDGES  = 131072;
constexpr int NGRAPHS = 16;

typedef short bf16x8 __attribute__((ext_vector_type(8)));
typedef float f32x4  __attribute__((ext_vector_type(4)));

__device__ __forceinline__ float leaky(float x, float s){ return x >= 0.0f ? x : s * x; }

__device__ __forceinline__ unsigned short f2bf(float f){
  unsigned u = __builtin_bit_cast(unsigned, f);
  u += 0x7FFFu + ((u >> 16) & 1u);          // round-to-nearest-even
  return (unsigned short)(u >> 16);
}

// ---------------- CSR build (edges fixed across layers; build once) ----------------
__global__ void k_deg(const int* __restrict__ dst, int* __restrict__ deg){
  int e = blockIdx.x * 256 + threadIdx.x;
  if (e < NEDGES) atomicAdd(&deg[dst[e]], 1);
}

__global__ __launch_bounds__(1024) void k_scan(const int* __restrict__ deg,
                                               int* __restrict__ rowptr,
                                               int* __restrict__ cursor){
  __shared__ int sums[1024];
  int t = threadIdx.x;
  int loc[16];
  int s = 0;
  #pragma unroll
  for (int i = 0; i < 16; i++){ loc[i] = deg[t*16 + i]; s += loc[i]; }
  sums[t] = s; __syncthreads();
  for (int off = 1; off < 1024; off <<= 1){
    int v = (t >= off) ? sums[t - off] : 0;
    __syncthreads();
    sums[t] += v;
    __syncthreads();
  }
  int base = (t > 0) ? sums[t-1] : 0;
  #pragma unroll
  for (int i = 0; i < 16; i++){
    rowptr[t*16 + i] = base; cursor[t*16 + i] = base; base += loc[i];
  }
  if (t == 1023) rowptr[NNODES] = base;
}

__global__ void k_scatter(const int* __restrict__ src, const int* __restrict__ dst,
                          int* __restrict__ cursor, int* __restrict__ perm){
  int e = blockIdx.x * 256 + threadIdx.x;
  if (e < NEDGES){ int p = atomicAdd(&cursor[dst[e]], 1); perm[p] = src[e]; }
}

__global__ void k_counts(const int* __restrict__ gid, float* __restrict__ counts){
  int n = blockIdx.x * 256 + threadIdx.x;
  if (n < NNODES) atomicAdd(&counts[gid[n]], 1.0f);
}

// ---------------- fp32 -> bf16 convert (contiguous) ----------------
__global__ void k_cvt(const float* __restrict__ in, unsigned short* __restrict__ out, int n4){
  int i = blockIdx.x * 256 + threadIdx.x;
  if (i >= n4) return;
  float4 v = ((const float4*)in)[i];
  ushort4 o; o.x = f2bf(v.x); o.y = f2bf(v.y); o.z = f2bf(v.z); o.w = f2bf(v.w);
  ((ushort4*)out)[i] = o;
}

// ---------------- fp32 [K][NN] -> bf16 transposed [NN][K] ----------------
__global__ __launch_bounds__(256) void k_cvt_t(const float* __restrict__ W,
                                               unsigned short* __restrict__ Wt,
                                               int K, int NN){
  __shared__ float tile[32][33];
  int n0 = blockIdx.x * 32, k0 = blockIdx.y * 32;
  int tx = threadIdx.x & 31, ty = threadIdx.x >> 5;   // 32 x 8
  #pragma unroll
  for (int i = 0; i < 4; i++)
    tile[ty + i*8][tx] = W[(size_t)(k0 + ty + i*8) * NN + n0 + tx];
  __syncthreads();
  #pragma unroll
  for (int i = 0; i < 4; i++)
    Wt[(size_t)(n0 + ty + i*8) * K + k0 + tx] = f2bf(tile[tx][ty + i*8]);
}

// ---------------- bf16 MFMA GEMM: C[M,NN] = A[M,K] @ Bt[NN,K]^T, 128x128 tile ----------------
__global__ __launch_bounds__(256) void k_gemm_bf16(const unsigned short* __restrict__ A,
                                                   const unsigned short* __restrict__ Bt,
                                                   float* __restrict__ C, int K, int NN){
  __shared__ unsigned short As[128 * 64];   // [row][k], XOR-swizzled
  __shared__ unsigned short Bs[128 * 64];   // [col][k], XOR-swizzled
  int t = threadIdx.x;
  int lane = t & 63, w = t >> 6;
  int wr = (w >> 1) * 64, wc = (w & 1) * 64;
  int l16 = lane & 15, lhi = lane >> 4;
  int rowA = blockIdx.y * 128;
  int colB = blockIdx.x * 128;
  f32x4 acc[4][4] = {};

  for (int k0 = 0; k0 < K; k0 += 64){
    __syncthreads();
    #pragma unroll
    for (int c = 0; c < 4; c++){
      int chunk = t + c * 256;            // 1024 chunks of 8 bf16
      int row = chunk >> 3, kc = (chunk & 7) * 8;
      int off = row * 128 + ((kc * 2) ^ ((row & 7) << 4));
      bf16x8 va = *(const bf16x8*)(A  + (size_t)(rowA + row) * K + k0 + kc);
      *(bf16x8*)((char*)As + off) = va;
      bf16x8 vb = *(const bf16x8*)(Bt + (size_t)(colB + row) * K + k0 + kc);
      *(bf16x8*)((char*)Bs + off) = vb;
    }
    __syncthreads();
    bf16x8 af[4][2], bfr[4][2];
    #pragma unroll
    for (int mi = 0; mi < 4; mi++){
      int row = wr + mi * 16 + l16;
      #pragma unroll
      for (int s = 0; s < 2; s++){
        int k = s * 32 + lhi * 8;
        int off = row * 128 + ((k * 2) ^ ((row & 7) << 4));
        af[mi][s] = *(const bf16x8*)((const char*)As + off);
      }
    }
    #pragma unroll
    for (int ni = 0; ni < 4; ni++){
      int row = wc + ni * 16 + l16;
      #pragma unroll
      for (int s = 0; s < 2; s++){
        int k = s * 32 + lhi * 8;
        int off = row * 128 + ((k * 2) ^ ((row & 7) << 4));
        bfr[ni][s] = *(const bf16x8*)((const char*)Bs + off);
      }
    }
    #pragma unroll
    for (int mi = 0; mi < 4; mi++)
      #pragma unroll
      for (int ni = 0; ni < 4; ni++){
        acc[mi][ni] = __builtin_amdgcn_mfma_f32_16x16x32_bf16(af[mi][0], bfr[ni][0], acc[mi][ni], 0, 0, 0);
        acc[mi][ni] = __builtin_amdgcn_mfma_f32_16x16x32_bf16(af[mi][1], bfr[ni][1], acc[mi][ni], 0, 0, 0);
      }
  }
  #pragma unroll
  for (int mi = 0; mi < 4; mi++){
    #pragma unroll
    for (int j = 0; j < 4; j++){
      int r = rowA + wr + mi * 16 + lhi * 4 + j;
      float* Cp = C + (size_t)r * NN + colB + wc + l16;
      #pragma unroll
      for (int ni = 0; ni < 4; ni++)
        Cp[ni * 16] = acc[mi][ni][j];
    }
  }
}

// ---------------- el/er: per (node,head) dot of h-row with attn vectors ----------------
template<int D>
__global__ __launch_bounds__(256) void k_elr(const float* __restrict__ HB,
                                             const float* __restrict__ al,
                                             const float* __restrict__ ar,
                                             float* __restrict__ el, float* __restrict__ er){
  int wid = threadIdx.x >> 6, lane = threadIdx.x & 63;
  int row = blockIdx.x * 4 + wid;          // row in [0, 2N)
  const float* hrow = HB + (size_t)(row >> 1) * (2*D) + (row & 1) * D;
  const float* alp  = al + (row & 1) * D;
  const float* arp  = ar + (row & 1) * D;
  float sl = 0.0f, sr = 0.0f;
  #pragma unroll
  for (int j = 0; j < D/64; j++){
    int c = lane + j*64;
    float v = hrow[c];
    sl += v * alp[c]; sr += v * arp[c];
  }
  for (int o = 32; o; o >>= 1){ sl += __shfl_xor(sl, o); sr += __shfl_xor(sr, o); }
  if (lane == 0){ el[row] = sl; er[row] = sr; }
}

// ---------------- attention: one wave per destination node; out = attn + residual ----------------
template<int D>
__global__ __launch_bounds__(256) void k_attn(const float* __restrict__ HB,
                                              float* __restrict__ RB,
                                              const float* __restrict__ el,
                                              const float* __restrict__ er,
                                              const int* __restrict__ rowptr,
                                              const int* __restrict__ perm){
  constexpr int CPT = (2*D)/64;
  int wid = threadIdx.x >> 6, lane = threadIdx.x & 63;
  int n = blockIdx.x * 4 + wid;
  int r0 = rowptr[n], r1 = rowptr[n+1];
  if (r0 == r1) return;   // no in-edges: output = residual already in RB
  float er0 = er[n*2], er1 = er[n*2+1];
  float mx0 = -1e30f, mx1 = -1e30f;
  for (int e = r0 + lane; e < r1; e += 64){
    int s = perm[e];
    mx0 = fmaxf(mx0, leaky(el[s*2]   + er0, 0.2f));
    mx1 = fmaxf(mx1, leaky(el[s*2+1] + er1, 0.2f));
  }
  for (int o = 32; o; o >>= 1){ mx0 = fmaxf(mx0, __shfl_xor(mx0, o)); mx1 = fmaxf(mx1, __shfl_xor(mx1, o)); }
  float sm0 = 0.0f, sm1 = 0.0f;
  for (int e = r0 + lane; e < r1; e += 64){
    int s = perm[e];
    sm0 += expf(leaky(el[s*2]   + er0, 0.2f) - mx0);
    sm1 += expf(leaky(el[s*2+1] + er1, 0.2f) - mx1);
  }
  for (int o = 32; o; o >>= 1){ sm0 += __shfl_xor(sm0, o); sm1 += __shfl_xor(sm1, o); }
  float inv0 = 1.0f / sm0, inv1 = 1.0f / sm1;
  float acc[CPT];
  #pragma unroll
  for (int j = 0; j < CPT; j++) acc[j] = 0.0f;
  for (int e = r0; e < r1; ++e){
    int s = perm[e];
    float a0 = expf(leaky(el[s*2]   + er0, 0.2f) - mx0) * inv0;
    float a1 = expf(leaky(el[s*2+1] + er1, 0.2f) - mx1) * inv1;
    const float* hrow = HB + (size_t)s * (2*D);
    #pragma unroll
    for (int j = 0; j < CPT; j++){
      int c = lane + j*64;
      acc[j] += (c < D ? a0 : a1) * hrow[c];
    }
  }
  float* rrow = RB + (size_t)n * (2*D);
  #pragma unroll
  for (int j = 0; j < CPT; j++){
    int c = lane + j*64;
    rrow[c] += acc[j];
  }
}

// ---------------- GraphNorm stats: per-column sums over nodes (columns = 2d) ----------------
__global__ __launch_bounds__(256) void k_stats(const float* __restrict__ R, int nn,
                                               float* __restrict__ gsum, float* __restrict__ gsq){
  __shared__ float rs[256], rq[256];
  int t = threadIdx.x, lane = t & 63, w = t >> 6;
  int nodeb = blockIdx.x * 256;
  for (int ch = 0; ch < nn; ch += 64){
    int col = ch + lane;
    float s = 0.0f, q = 0.0f;
    const float* base = R + (size_t)(nodeb + w*64) * nn + col;
    for (int i = 0; i < 64; i++){ float v = base[(size_t)i * nn]; s += v; q += v*v; }
    rs[t] = s; rq[t] = q; __syncthreads();
    if (t < 64){
      float ss = rs[t] + rs[t+64] + rs[t+128] + rs[t+192];
      float qq = rq[t] + rq[t+64] + rq[t+128] + rq[t+192];
      atomicAdd(&gsum[ch + t], ss);
      atomicAdd(&gsq [ch + t], qq);
    }
    __syncthreads();
  }
}

__global__ void k_finstats(const float* __restrict__ gsum, const float* __restrict__ gsq,
                           const float* __restrict__ alpha,
                           float* __restrict__ mean, float* __restrict__ rstd, int d){
  int t = threadIdx.x;
  if (t >= d) return;
  float s = gsum[t] + gsum[t + d];
  float q = gsq[t]  + gsq[t + d];
  const float M = (float)(2 * NNODES);
  float m   = s / M;
  float msq = q / M;
  float a   = alpha[t];
  float var = msq - a * m * m * (2.0f - a);   // E[(x-am)^2] = E[x^2] - a m^2 (2-a)
  mean[t] = m;
  rstd[t] = rsqrtf(var + 1e-5f);
}

// ---------------- norm apply + leaky + head-mean + graph pooling (fused), bf16 X-out -------
__global__ __launch_bounds__(256) void k_norm_pool(const float* __restrict__ R,
                                                   unsigned short* __restrict__ Xn, // bf16 next-layer input (or null)
                                                   const float* __restrict__ mean,
                                                   const float* __restrict__ rstd,
                                                   const float* __restrict__ gamma,
                                                   const float* __restrict__ beta,
                                                   const float* __restrict__ alpha,
                                                   float* __restrict__ pool, int d, int loff){
  int t = threadIdx.x, lane = t & 63, w = t >> 6;
  int c = blockIdx.y * 64 + lane;
  int nodeb = blockIdx.x * 256 + w * 64;
  int g = blockIdx.x >> 2;                 // 4 node-blocks per graph (1024 nodes/graph)
  float m  = mean[c], rs = rstd[c], ga = gamma[c], be = beta[c];
  float am = alpha[c] * m;
  int nn = 2 * d;
  const float* r0 = R + (size_t)nodeb * nn + c;
  float accp = 0.0f;
  for (int i = 0; i < 64; i++){
    float v0 = r0[(size_t)i * nn];
    float v1 = r0[(size_t)i * nn + d];
    float y0 = ga * (v0 - am) * rs + be; y0 = y0 >= 0.0f ? y0 : 0.01f * y0;
    float y1 = ga * (v1 - am) * rs + be; y1 = y1 >= 0.0f ? y1 : 0.01f * y1;
    if (Xn){
      Xn[(size_t)(nodeb + i) * nn + c]     = f2bf(y0);
      Xn[(size_t)(nodeb + i) * nn + d + c] = f2bf(y1);
    }
    accp += y0 + y1;
  }
  accp *= 0.5f;
  __shared__ float red[256];
  red[t] = accp; __syncthreads();
  if (t < 64){
    float s = red[t] + red[t+64] + red[t+128] + red[t+192];
    atomicAdd(&pool[g * 896 + loff + blockIdx.y * 64 + t], s);
  }
}

__global__ void k_final(const float* __restrict__ pool, const float* __restrict__ counts,
                        float* __restrict__ out){
  int idx = blockIdx.x * 256 + threadIdx.x;
  if (idx >= NGRAPHS * 896) return;
  int g = idx / 896;
  float v = pool[idx] / counts[g];
  out[idx] = v >= 0.0f ? v : 0.01f * v;
}

// ---------------------------------------------------------------------------------------
extern "C" void kernel_launch(void* const* d_in, const int* in_sizes, int n_in,
                              void* d_out, int out_size, void* d_ws, size_t ws_size,
                              hipStream_t stream){
  const float* x0 = (const float*)d_in[0];
  const float *W[3], *AL[3], *AR[3], *RW[3], *GA[3], *BE[3], *ALP[3];
  for (int l = 0; l < 3; l++){
    const int b = 1 + l*7;
    W[l]  = (const float*)d_in[b+0];
    AL[l] = (const float*)d_in[b+1];
    AR[l] = (const float*)d_in[b+2];
    RW[l] = (const float*)d_in[b+3];
    GA[l] = (const float*)d_in[b+4];
    BE[l] = (const float*)d_in[b+5];
    ALP[l]= (const float*)d_in[b+6];
  }
  const int* esrc = (const int*)d_in[22];
  const int* edst = (const int*)d_in[23];
  const int* gid  = (const int*)d_in[24];
  float* out = (float*)d_out;

  char* p = (char*)d_ws;
  auto carve = [&](size_t bytes)->void*{
    void* r = (void*)p; p += (bytes + 255) & ~(size_t)255; return r;
  };
  float* HB     = (float*)carve((size_t)NNODES * 1024 * 4);  // h = x@W    [N, 2d] fp32
  float* RB     = (float*)carve((size_t)NNODES * 1024 * 4);  // r then out [N, 2d] fp32
  unsigned short* X0b = (unsigned short*)carve((size_t)NNODES * 128 * 2);  // bf16 layer-0 input
  unsigned short* XA  = (unsigned short*)carve((size_t)NNODES * 256 * 2);  // bf16 y0
  unsigned short* XB  = (unsigned short*)carve((size_t)NNODES * 512 * 2);  // bf16 y1
  unsigned short* Wt  = (unsigned short*)carve((size_t)1024 * 512 * 2);    // bf16 W^T (max)
  unsigned short* RWt = (unsigned short*)carve((size_t)1024 * 512 * 2);    // bf16 resW^T (max)
  float* el     = (float*)carve((size_t)NNODES * 2 * 4);
  float* er     = (float*)carve((size_t)NNODES * 2 * 4);
  int*   deg    = (int*)  carve((size_t)NNODES * 4);
  int*   rowptr = (int*)  carve((size_t)(NNODES + 1) * 4);
  int*   cursor = (int*)  carve((size_t)NNODES * 4);
  int*   perm   = (int*)  carve((size_t)NEDGES * 4);
  float* stats  = (float*)carve(2048 * 4);                   // gsum[1024] | gsq[1024]
  float* meanb  = (float*)carve(512 * 4);
  float* rstdb  = (float*)carve(512 * 4);
  float* pool   = (float*)carve((size_t)NGRAPHS * 896 * 4);
  float* countsF= (float*)carve((size_t)NGRAPHS * 4);
  (void)ws_size; (void)in_sizes; (void)n_in; (void)out_size;

  hipMemsetAsync(deg, 0, NNODES * 4, stream);
  hipMemsetAsync(pool, 0, NGRAPHS * 896 * 4, stream);
  hipMemsetAsync(countsF, 0, NGRAPHS * 4, stream);

  k_deg    <<<NEDGES/256, 256, 0, stream>>>(edst, deg);
  k_scan   <<<1, 1024, 0, stream>>>(deg, rowptr, cursor);
  k_scatter<<<NEDGES/256, 256, 0, stream>>>(esrc, edst, cursor, perm);
  k_counts <<<NNODES/256, 256, 0, stream>>>(gid, countsF);
  k_cvt    <<<(NNODES*128/4 + 255)/256, 256, 0, stream>>>(x0, X0b, NNODES*128/4);

  const unsigned short* xin = X0b;
  int loff = 0;
  const int dims[3] = {128, 256, 512};
  for (int l = 0; l < 3; l++){
    int d = dims[l], nn = 2*d;
    dim3 gt(nn/32, d/32);
    k_cvt_t<<<gt, 256, 0, stream>>>(W[l],  Wt,  d, nn);
    k_cvt_t<<<gt, 256, 0, stream>>>(RW[l], RWt, d, nn);
    dim3 gg(nn/128, NNODES/128);
    k_gemm_bf16<<<gg, 256, 0, stream>>>(xin, Wt,  HB, d, nn);
    k_gemm_bf16<<<gg, 256, 0, stream>>>(xin, RWt, RB, d, nn);
    if (d == 128){
      k_elr <128><<<NNODES*2/4, 256, 0, stream>>>(HB, AL[l], AR[l], el, er);
      k_attn<128><<<NNODES/4,   256, 0, stream>>>(HB, RB, el, er, rowptr, perm);
    } else if (d == 256){
      k_elr <256><<<NNODES*2/4, 256, 0, stream>>>(HB, AL[l], AR[l], el, er);
      k_attn<256><<<NNODES/4,   256, 0, stream>>>(HB, RB, el, er, rowptr, perm);
    } else {
      k_elr <512><<<NNODES*2/4, 256, 0, stream>>>(HB, AL[l], AR[l], el, er);
      k_attn<512><<<NNODES/4,   256, 0, stream>>>(HB, RB, el, er, rowptr, perm);
    }
    hipMemsetAsync(stats, 0, 2048 * 4, stream);
    k_stats   <<<NNODES/256, 256, 0, stream>>>(RB, nn, stats, stats + 1024);
    k_finstats<<<1, 512, 0, stream>>>(stats, stats + 1024, ALP[l], meanb, rstdb, d);
    unsigned short* xn = (l == 0) ? XA : (l == 1) ? XB : nullptr;
    dim3 gn(NNODES/256, d/64);
    k_norm_pool<<<gn, 256, 0, stream>>>(RB, xn, meanb, rstdb, GA[l], BE[l], ALP[l], pool, d, loff);
    xin = xn; loff += d;
  }
  k_final<<<(NGRAPHS*896 + 255)/256, 256, 0, stream>>>(pool, countsF, out);
}

// Round 3
// 510.847 us; speedup vs baseline: 2.5108x; 1.4083x over previous
//
#include <hip/hip_runtime.h>
#include <math.h>

constexpr int NNODES  = 16384;
constexpr int NEDGES  = 131072;
constexpr int NGRAPHS = 16;

typedef short bf16x8 __attribute__((ext_vector_type(8)));
typedef float f32x4  __attribute__((ext_vector_type(4)));

__device__ __forceinline__ float leaky(float x, float s){ return x >= 0.0f ? x : s * x; }

__device__ __forceinline__ unsigned short f2bf(float f){
  unsigned u = __builtin_bit_cast(unsigned, f);
  u += 0x7FFFu + ((u >> 16) & 1u);          // round-to-nearest-even
  return (unsigned short)(u >> 16);
}

// ---------------- CSR build (edges fixed across layers; build once) ----------------
__global__ void k_deg(const int* __restrict__ dst, int* __restrict__ deg){
  int e = blockIdx.x * 256 + threadIdx.x;
  if (e < NEDGES) atomicAdd(&deg[dst[e]], 1);
}

__global__ __launch_bounds__(1024) void k_scan(const int* __restrict__ deg,
                                               int* __restrict__ rowptr,
                                               int* __restrict__ cursor){
  __shared__ int sums[1024];
  int t = threadIdx.x;
  int loc[16];
  int s = 0;
  #pragma unroll
  for (int i = 0; i < 16; i++){ loc[i] = deg[t*16 + i]; s += loc[i]; }
  sums[t] = s; __syncthreads();
  for (int off = 1; off < 1024; off <<= 1){
    int v = (t >= off) ? sums[t - off] : 0;
    __syncthreads();
    sums[t] += v;
    __syncthreads();
  }
  int base = (t > 0) ? sums[t-1] : 0;
  #pragma unroll
  for (int i = 0; i < 16; i++){
    rowptr[t*16 + i] = base; cursor[t*16 + i] = base; base += loc[i];
  }
  if (t == 1023) rowptr[NNODES] = base;
}

__global__ void k_scatter(const int* __restrict__ src, const int* __restrict__ dst,
                          int* __restrict__ cursor, int* __restrict__ perm){
  int e = blockIdx.x * 256 + threadIdx.x;
  if (e < NEDGES){ int p = atomicAdd(&cursor[dst[e]], 1); perm[p] = src[e]; }
}

// ---- graph-size counts: LDS histogram per block, one global atomic per (block,graph) ----
__global__ __launch_bounds__(256) void k_counts(const int* __restrict__ gid, float* __restrict__ counts){
  __shared__ int h[NGRAPHS];
  int t = threadIdx.x;
  if (t < NGRAPHS) h[t] = 0;
  __syncthreads();
  int base = blockIdx.x * 1024;
  #pragma unroll
  for (int i = 0; i < 4; i++)
    atomicAdd(&h[gid[base + t + i*256]], 1);
  __syncthreads();
  if (t < NGRAPHS && h[t] > 0) atomicAdd(&counts[t], (float)h[t]);
}

// ---------------- fp32 -> bf16 convert (contiguous) ----------------
__global__ void k_cvt(const float* __restrict__ in, unsigned short* __restrict__ out, int n4){
  int i = blockIdx.x * 256 + threadIdx.x;
  if (i >= n4) return;
  float4 v = ((const float4*)in)[i];
  ushort4 o; o.x = f2bf(v.x); o.y = f2bf(v.y); o.z = f2bf(v.z); o.w = f2bf(v.w);
  ((ushort4*)out)[i] = o;
}

// ---------------- fp32 [K][NN] -> bf16 transposed [NN][K] ----------------
__global__ __launch_bounds__(256) void k_cvt_t(const float* __restrict__ W,
                                               unsigned short* __restrict__ Wt,
                                               int K, int NN){
  __shared__ float tile[32][33];
  int n0 = blockIdx.x * 32, k0 = blockIdx.y * 32;
  int tx = threadIdx.x & 31, ty = threadIdx.x >> 5;   // 32 x 8
  #pragma unroll
  for (int i = 0; i < 4; i++)
    tile[ty + i*8][tx] = W[(size_t)(k0 + ty + i*8) * NN + n0 + tx];
  __syncthreads();
  #pragma unroll
  for (int i = 0; i < 4; i++)
    Wt[(size_t)(n0 + ty + i*8) * K + k0 + tx] = f2bf(tile[tx][ty + i*8]);
}

// ---------------- bf16 MFMA GEMM: C[M,NN] = A[M,K] @ Bt[NN,K]^T, 128x128 tile ----------------
__global__ __launch_bounds__(256) void k_gemm_bf16(const unsigned short* __restrict__ A,
                                                   const unsigned short* __restrict__ Bt,
                                                   float* __restrict__ C, int K, int NN){
  __shared__ unsigned short As[128 * 64];   // [row][k], XOR-swizzled
  __shared__ unsigned short Bs[128 * 64];   // [col][k], XOR-swizzled
  int t = threadIdx.x;
  int lane = t & 63, w = t >> 6;
  int wr = (w >> 1) * 64, wc = (w & 1) * 64;
  int l16 = lane & 15, lhi = lane >> 4;
  int rowA = blockIdx.y * 128;
  int colB = blockIdx.x * 128;
  f32x4 acc[4][4] = {};

  for (int k0 = 0; k0 < K; k0 += 64){
    __syncthreads();
    #pragma unroll
    for (int c = 0; c < 4; c++){
      int chunk = t + c * 256;            // 1024 chunks of 8 bf16
      int row = chunk >> 3, kc = (chunk & 7) * 8;
      int off = row * 128 + ((kc * 2) ^ ((row & 7) << 4));
      bf16x8 va = *(const bf16x8*)(A  + (size_t)(rowA + row) * K + k0 + kc);
      *(bf16x8*)((char*)As + off) = va;
      bf16x8 vb = *(const bf16x8*)(Bt + (size_t)(colB + row) * K + k0 + kc);
      *(bf16x8*)((char*)Bs + off) = vb;
    }
    __syncthreads();
    bf16x8 af[4][2], bfr[4][2];
    #pragma unroll
    for (int mi = 0; mi < 4; mi++){
      int row = wr + mi * 16 + l16;
      #pragma unroll
      for (int s = 0; s < 2; s++){
        int k = s * 32 + lhi * 8;
        int off = row * 128 + ((k * 2) ^ ((row & 7) << 4));
        af[mi][s] = *(const bf16x8*)((const char*)As + off);
      }
    }
    #pragma unroll
    for (int ni = 0; ni < 4; ni++){
      int row = wc + ni * 16 + l16;
      #pragma unroll
      for (int s = 0; s < 2; s++){
        int k = s * 32 + lhi * 8;
        int off = row * 128 + ((k * 2) ^ ((row & 7) << 4));
        bfr[ni][s] = *(const bf16x8*)((const char*)Bs + off);
      }
    }
    #pragma unroll
    for (int mi = 0; mi < 4; mi++)
      #pragma unroll
      for (int ni = 0; ni < 4; ni++){
        acc[mi][ni] = __builtin_amdgcn_mfma_f32_16x16x32_bf16(af[mi][0], bfr[ni][0], acc[mi][ni], 0, 0, 0);
        acc[mi][ni] = __builtin_amdgcn_mfma_f32_16x16x32_bf16(af[mi][1], bfr[ni][1], acc[mi][ni], 0, 0, 0);
      }
  }
  #pragma unroll
  for (int mi = 0; mi < 4; mi++){
    #pragma unroll
    for (int j = 0; j < 4; j++){
      int r = rowA + wr + mi * 16 + lhi * 4 + j;
      float* Cp = C + (size_t)r * NN + colB + wc + l16;
      #pragma unroll
      for (int ni = 0; ni < 4; ni++)
        Cp[ni * 16] = acc[mi][ni][j];
    }
  }
}

// ---------------- el/er: per (node,head) dot of h-row with attn vectors ----------------
template<int D>
__global__ __launch_bounds__(256) void k_elr(const float* __restrict__ HB,
                                             const float* __restrict__ al,
                                             const float* __restrict__ ar,
                                             float* __restrict__ el, float* __restrict__ er){
  int wid = threadIdx.x >> 6, lane = threadIdx.x & 63;
  int row = blockIdx.x * 4 + wid;          // row in [0, 2N)
  const float* hrow = HB + (size_t)(row >> 1) * (2*D) + (row & 1) * D;
  const float* alp  = al + (row & 1) * D;
  const float* arp  = ar + (row & 1) * D;
  float sl = 0.0f, sr = 0.0f;
  #pragma unroll
  for (int j = 0; j < D/64; j++){
    int c = lane + j*64;
    float v = hrow[c];
    sl += v * alp[c]; sr += v * arp[c];
  }
  for (int o = 32; o; o >>= 1){ sl += __shfl_xor(sl, o); sr += __shfl_xor(sr, o); }
  if (lane == 0){ el[row] = sl; er[row] = sr; }
}

// ---------------- attention: one wave per destination node; out = attn + residual ----------------
template<int D>
__global__ __launch_bounds__(256) void k_attn(const float* __restrict__ HB,
                                              float* __restrict__ RB,
                                              const float* __restrict__ el,
                                              const float* __restrict__ er,
                                              const int* __restrict__ rowptr,
                                              const int* __restrict__ perm){
  constexpr int CPT = (2*D)/64;
  int wid = threadIdx.x >> 6, lane = threadIdx.x & 63;
  int n = blockIdx.x * 4 + wid;
  int r0 = rowptr[n], r1 = rowptr[n+1];
  if (r0 == r1) return;   // no in-edges: output = residual already in RB
  float er0 = er[n*2], er1 = er[n*2+1];
  float mx0 = -1e30f, mx1 = -1e30f;
  for (int e = r0 + lane; e < r1; e += 64){
    int s = perm[e];
    mx0 = fmaxf(mx0, leaky(el[s*2]   + er0, 0.2f));
    mx1 = fmaxf(mx1, leaky(el[s*2+1] + er1, 0.2f));
  }
  for (int o = 32; o; o >>= 1){ mx0 = fmaxf(mx0, __shfl_xor(mx0, o)); mx1 = fmaxf(mx1, __shfl_xor(mx1, o)); }
  float sm0 = 0.0f, sm1 = 0.0f;
  for (int e = r0 + lane; e < r1; e += 64){
    int s = perm[e];
    sm0 += expf(leaky(el[s*2]   + er0, 0.2f) - mx0);
    sm1 += expf(leaky(el[s*2+1] + er1, 0.2f) - mx1);
  }
  for (int o = 32; o; o >>= 1){ sm0 += __shfl_xor(sm0, o); sm1 += __shfl_xor(sm1, o); }
  float inv0 = 1.0f / sm0, inv1 = 1.0f / sm1;
  float acc[CPT];
  #pragma unroll
  for (int j = 0; j < CPT; j++) acc[j] = 0.0f;
  for (int e = r0; e < r1; ++e){
    int s = perm[e];
    float a0 = expf(leaky(el[s*2]   + er0, 0.2f) - mx0) * inv0;
    float a1 = expf(leaky(el[s*2+1] + er1, 0.2f) - mx1) * inv1;
    const float* hrow = HB + (size_t)s * (2*D);
    #pragma unroll
    for (int j = 0; j < CPT; j++){
      int c = lane + j*64;
      acc[j] += (c < D ? a0 : a1) * hrow[c];
    }
  }
  float* rrow = RB + (size_t)n * (2*D);
  #pragma unroll
  for (int j = 0; j < CPT; j++){
    int c = lane + j*64;
    rrow[c] += acc[j];
  }
}

// ---------------- GraphNorm stats: per-column sums over nodes (columns = 2d) ----------------
__global__ __launch_bounds__(256) void k_stats(const float* __restrict__ R, int nn,
                                               float* __restrict__ gsum, float* __restrict__ gsq){
  __shared__ float rs[256], rq[256];
  int t = threadIdx.x, lane = t & 63, w = t >> 6;
  int nodeb = blockIdx.x * 256;
  for (int ch = 0; ch < nn; ch += 64){
    int col = ch + lane;
    float s = 0.0f, q = 0.0f;
    const float* base = R + (size_t)(nodeb + w*64) * nn + col;
    for (int i = 0; i < 64; i++){ float v = base[(size_t)i * nn]; s += v; q += v*v; }
    rs[t] = s; rq[t] = q; __syncthreads();
    if (t < 64){
      float ss = rs[t] + rs[t+64] + rs[t+128] + rs[t+192];
      float qq = rq[t] + rq[t+64] + rq[t+128] + rq[t+192];
      atomicAdd(&gsum[ch + t], ss);
      atomicAdd(&gsq [ch + t], qq);
    }
    __syncthreads();
  }
}

__global__ void k_finstats(const float* __restrict__ gsum, const float* __restrict__ gsq,
                           const float* __restrict__ alpha,
                           float* __restrict__ mean, float* __restrict__ rstd, int d){
  int t = threadIdx.x;
  if (t >= d) return;
  float s = gsum[t] + gsum[t + d];
  float q = gsq[t]  + gsq[t + d];
  const float M = (float)(2 * NNODES);
  float m   = s / M;
  float msq = q / M;
  float a   = alpha[t];
  float var = msq - a * m * m * (2.0f - a);   // E[(x-am)^2] = E[x^2] - a m^2 (2-a)
  mean[t] = m;
  rstd[t] = rsqrtf(var + 1e-5f);
}

// ---------------- norm apply + leaky + head-mean + graph pooling (fused), bf16 X-out -------
__global__ __launch_bounds__(256) void k_norm_pool(const float* __restrict__ R,
                                                   unsigned short* __restrict__ Xn, // bf16 next-layer input (or null)
                                                   const float* __restrict__ mean,
                                                   const float* __restrict__ rstd,
                                                   const float* __restrict__ gamma,
                                                   const float* __restrict__ beta,
                                                   const float* __restrict__ alpha,
                                                   float* __restrict__ pool, int d, int loff){
  int t = threadIdx.x, lane = t & 63, w = t >> 6;
  int c = blockIdx.y * 64 + lane;
  int nodeb = blockIdx.x * 256 + w * 64;
  int g = blockIdx.x >> 2;                 // 4 node-blocks per graph (1024 nodes/graph)
  float m  = mean[c], rs = rstd[c], ga = gamma[c], be = beta[c];
  float am = alpha[c] * m;
  int nn = 2 * d;
  const float* r0 = R + (size_t)nodeb * nn + c;
  float accp = 0.0f;
  for (int i = 0; i < 64; i++){
    float v0 = r0[(size_t)i * nn];
    float v1 = r0[(size_t)i * nn + d];
    float y0 = ga * (v0 - am) * rs + be; y0 = y0 >= 0.0f ? y0 : 0.01f * y0;
    float y1 = ga * (v1 - am) * rs + be; y1 = y1 >= 0.0f ? y1 : 0.01f * y1;
    if (Xn){
      Xn[(size_t)(nodeb + i) * nn + c]     = f2bf(y0);
      Xn[(size_t)(nodeb + i) * nn + d + c] = f2bf(y1);
    }
    accp += y0 + y1;
  }
  accp *= 0.5f;
  __shared__ float red[256];
  red[t] = accp; __syncthreads();
  if (t < 64){
    float s = red[t] + red[t+64] + red[t+128] + red[t+192];
    atomicAdd(&pool[g * 896 + loff + blockIdx.y * 64 + t], s);
  }
}

__global__ void k_final(const float* __restrict__ pool, const float* __restrict__ counts,
                        float* __restrict__ out){
  int idx = blockIdx.x * 256 + threadIdx.x;
  if (idx >= NGRAPHS * 896) return;
  int g = idx / 896;
  float v = pool[idx] / counts[g];
  out[idx] = v >= 0.0f ? v : 0.01f * v;
}

// ---------------------------------------------------------------------------------------
extern "C" void kernel_launch(void* const* d_in, const int* in_sizes, int n_in,
                              void* d_out, int out_size, void* d_ws, size_t ws_size,
                              hipStream_t stream){
  const float* x0 = (const float*)d_in[0];
  const float *W[3], *AL[3], *AR[3], *RW[3], *GA[3], *BE[3], *ALP[3];
  for (int l = 0; l < 3; l++){
    const int b = 1 + l*7;
    W[l]  = (const float*)d_in[b+0];
    AL[l] = (const float*)d_in[b+1];
    AR[l] = (const float*)d_in[b+2];
    RW[l] = (const float*)d_in[b+3];
    GA[l] = (const float*)d_in[b+4];
    BE[l] = (const float*)d_in[b+5];
    ALP[l]= (const float*)d_in[b+6];
  }
  const int* esrc = (const int*)d_in[22];
  const int* edst = (const int*)d_in[23];
  const int* gid  = (const int*)d_in[24];
  float* out = (float*)d_out;

  char* p = (char*)d_ws;
  auto carve = [&](size_t bytes)->void*{
    void* r = (void*)p; p += (bytes + 255) & ~(size_t)255; return r;
  };
  float* HB     = (float*)carve((size_t)NNODES * 1024 * 4);  // h = x@W    [N, 2d] fp32
  float* RB     = (float*)carve((size_t)NNODES * 1024 * 4);  // r then out [N, 2d] fp32
  unsigned short* X0b = (unsigned short*)carve((size_t)NNODES * 128 * 2);  // bf16 layer-0 input
  unsigned short* XA  = (unsigned short*)carve((size_t)NNODES * 256 * 2);  // bf16 y0
  unsigned short* XB  = (unsigned short*)carve((size_t)NNODES * 512 * 2);  // bf16 y1
  unsigned short* Wt  = (unsigned short*)carve((size_t)1024 * 512 * 2);    // bf16 W^T (max)
  unsigned short* RWt = (unsigned short*)carve((size_t)1024 * 512 * 2);    // bf16 resW^T (max)
  float* el     = (float*)carve((size_t)NNODES * 2 * 4);
  float* er     = (float*)carve((size_t)NNODES * 2 * 4);
  int*   deg    = (int*)  carve((size_t)NNODES * 4);
  int*   rowptr = (int*)  carve((size_t)(NNODES + 1) * 4);
  int*   cursor = (int*)  carve((size_t)NNODES * 4);
  int*   perm   = (int*)  carve((size_t)NEDGES * 4);
  float* stats  = (float*)carve(2048 * 4);                   // gsum[1024] | gsq[1024]
  float* meanb  = (float*)carve(512 * 4);
  float* rstdb  = (float*)carve(512 * 4);
  float* pool   = (float*)carve((size_t)NGRAPHS * 896 * 4);
  float* countsF= (float*)carve((size_t)NGRAPHS * 4);
  (void)ws_size; (void)in_sizes; (void)n_in; (void)out_size;

  hipMemsetAsync(deg, 0, NNODES * 4, stream);
  hipMemsetAsync(pool, 0, NGRAPHS * 896 * 4, stream);
  hipMemsetAsync(countsF, 0, NGRAPHS * 4, stream);

  k_deg    <<<NEDGES/256, 256, 0, stream>>>(edst, deg);
  k_scan   <<<1, 1024, 0, stream>>>(deg, rowptr, cursor);
  k_scatter<<<NEDGES/256, 256, 0, stream>>>(esrc, edst, cursor, perm);
  k_counts <<<NNODES/1024, 256, 0, stream>>>(gid, countsF);
  k_cvt    <<<(NNODES*128/4 + 255)/256, 256, 0, stream>>>(x0, X0b, NNODES*128/4);

  const unsigned short* xin = X0b;
  int loff = 0;
  const int dims[3] = {128, 256, 512};
  for (int l = 0; l < 3; l++){
    int d = dims[l], nn = 2*d;
    dim3 gt(nn/32, d/32);
    k_cvt_t<<<gt, 256, 0, stream>>>(W[l],  Wt,  d, nn);
    k_cvt_t<<<gt, 256, 0, stream>>>(RW[l], RWt, d, nn);
    dim3 gg(nn/128, NNODES/128);
    k_gemm_bf16<<<gg, 256, 0, stream>>>(xin, Wt,  HB, d, nn);
    k_gemm_bf16<<<gg, 256, 0, stream>>>(xin, RWt, RB, d, nn);
    if (d == 128){
      k_elr <128><<<NNODES*2/4, 256, 0, stream>>>(HB, AL[l], AR[l], el, er);
      k_attn<128><<<NNODES/4,   256, 0, stream>>>(HB, RB, el, er, rowptr, perm);
    } else if (d == 256){
      k_elr <256><<<NNODES*2/4, 256, 0, stream>>>(HB, AL[l], AR[l], el, er);
      k_attn<256><<<NNODES/4,   256, 0, stream>>>(HB, RB, el, er, rowptr, perm);
    } else {
      k_elr <512><<<NNODES*2/4, 256, 0, stream>>>(HB, AL[l], AR[l], el, er);
      k_attn<512><<<NNODES/4,   256, 0, stream>>>(HB, RB, el, er, rowptr, perm);
    }
    hipMemsetAsync(stats, 0, 2048 * 4, stream);
    k_stats   <<<NNODES/256, 256, 0, stream>>>(RB, nn, stats, stats + 1024);
    k_finstats<<<1, 512, 0, stream>>>(stats, stats + 1024, ALP[l], meanb, rstdb, d);
    unsigned short* xn = (l == 0) ? XA : (l == 1) ? XB : nullptr;
    dim3 gn(NNODES/256, d/64);
    k_norm_pool<<<gn, 256, 0, stream>>>(RB, xn, meanb, rstdb, GA[l], BE[l], ALP[l], pool, d, loff);
    xin = xn; loff += d;
  }
  k_final<<<(NGRAPHS*896 + 255)/256, 256, 0, stream>>>(pool, countsF, out);
}

// Round 4
// 438.755 us; speedup vs baseline: 2.9234x; 1.1643x over previous
//
#include <hip/hip_runtime.h>
#include <math.h>

constexpr int NNODES  = 16384;
constexpr int NEDGES  = 131072;
constexpr int NGRAPHS = 16;

typedef short bf16x8 __attribute__((ext_vector_type(8)));
typedef short bf16x4 __attribute__((ext_vector_type(4)));
typedef float f32x4  __attribute__((ext_vector_type(4)));

__device__ __forceinline__ float leaky(float x, float s){ return x >= 0.0f ? x : s * x; }

__device__ __forceinline__ unsigned short f2bf(float f){
  unsigned u = __builtin_bit_cast(unsigned, f);
  u += 0x7FFFu + ((u >> 16) & 1u);          // round-to-nearest-even
  return (unsigned short)(u >> 16);
}
__device__ __forceinline__ float bf2f(unsigned short u){
  unsigned x = (unsigned)u << 16; return __builtin_bit_cast(float, x);
}

// ---------------- CSR build (edges fixed across layers; build once) ----------------
__global__ void k_deg(const int* __restrict__ dst, int* __restrict__ deg){
  int e = blockIdx.x * 256 + threadIdx.x;
  if (e < NEDGES) atomicAdd(&deg[dst[e]], 1);
}

__global__ __launch_bounds__(1024) void k_scan(const int* __restrict__ deg,
                                               int* __restrict__ rowptr,
                                               int* __restrict__ cursor){
  __shared__ int sums[1024];
  int t = threadIdx.x;
  int loc[16];
  int s = 0;
  #pragma unroll
  for (int i = 0; i < 16; i++){ loc[i] = deg[t*16 + i]; s += loc[i]; }
  sums[t] = s; __syncthreads();
  for (int off = 1; off < 1024; off <<= 1){
    int v = (t >= off) ? sums[t - off] : 0;
    __syncthreads();
    sums[t] += v;
    __syncthreads();
  }
  int base = (t > 0) ? sums[t-1] : 0;
  #pragma unroll
  for (int i = 0; i < 16; i++){
    rowptr[t*16 + i] = base; cursor[t*16 + i] = base; base += loc[i];
  }
  if (t == 1023) rowptr[NNODES] = base;
}

__global__ void k_scatter(const int* __restrict__ src, const int* __restrict__ dst,
                          int* __restrict__ cursor, int* __restrict__ perm){
  int e = blockIdx.x * 256 + threadIdx.x;
  if (e < NEDGES){ int p = atomicAdd(&cursor[dst[e]], 1); perm[p] = src[e]; }
}

// ---- graph-size counts: LDS histogram per block, one global atomic per (block,graph) ----
__global__ __launch_bounds__(256) void k_counts(const int* __restrict__ gid, float* __restrict__ counts){
  __shared__ int h[NGRAPHS];
  int t = threadIdx.x;
  if (t < NGRAPHS) h[t] = 0;
  __syncthreads();
  int base = blockIdx.x * 1024;
  #pragma unroll
  for (int i = 0; i < 4; i++)
    atomicAdd(&h[gid[base + t + i*256]], 1);
  __syncthreads();
  if (t < NGRAPHS && h[t] > 0) atomicAdd(&counts[t], (float)h[t]);
}

// ---------------- fp32 -> bf16 convert (contiguous) ----------------
__global__ void k_cvt(const float* __restrict__ in, unsigned short* __restrict__ out, int n4){
  int i = blockIdx.x * 256 + threadIdx.x;
  if (i >= n4) return;
  float4 v = ((const float4*)in)[i];
  ushort4 o; o.x = f2bf(v.x); o.y = f2bf(v.y); o.z = f2bf(v.z); o.w = f2bf(v.w);
  ((ushort4*)out)[i] = o;
}

// ---------------- fp32 [K][NN] -> bf16 transposed [NN][K] ----------------
__global__ __launch_bounds__(256) void k_cvt_t(const float* __restrict__ W,
                                               unsigned short* __restrict__ Wt,
                                               int K, int NN){
  __shared__ float tile[32][33];
  int n0 = blockIdx.x * 32, k0 = blockIdx.y * 32;
  int tx = threadIdx.x & 31, ty = threadIdx.x >> 5;   // 32 x 8
  #pragma unroll
  for (int i = 0; i < 4; i++)
    tile[ty + i*8][tx] = W[(size_t)(k0 + ty + i*8) * NN + n0 + tx];
  __syncthreads();
  #pragma unroll
  for (int i = 0; i < 4; i++)
    Wt[(size_t)(n0 + ty + i*8) * K + k0 + tx] = f2bf(tile[tx][ty + i*8]);
}

// ---------------- bf16 MFMA GEMM: C[M,NN] = A[M,K] @ Bt[NN,K]^T, 128x128 tile ----------------
// BF16OUT: store C as bf16 (for the attention gather buffer); else fp32.
template<bool BF16OUT>
__global__ __launch_bounds__(256) void k_gemm_bf16(const unsigned short* __restrict__ A,
                                                   const unsigned short* __restrict__ Bt,
                                                   void* __restrict__ Cv, int K, int NN){
  __shared__ unsigned short As[128 * 64];   // [row][k], XOR-swizzled
  __shared__ unsigned short Bs[128 * 64];   // [col][k], XOR-swizzled
  int t = threadIdx.x;
  int lane = t & 63, w = t >> 6;
  int wr = (w >> 1) * 64, wc = (w & 1) * 64;
  int l16 = lane & 15, lhi = lane >> 4;
  int rowA = blockIdx.y * 128;
  int colB = blockIdx.x * 128;
  f32x4 acc[4][4] = {};

  for (int k0 = 0; k0 < K; k0 += 64){
    __syncthreads();
    #pragma unroll
    for (int c = 0; c < 4; c++){
      int chunk = t + c * 256;            // 1024 chunks of 8 bf16
      int row = chunk >> 3, kc = (chunk & 7) * 8;
      int off = row * 128 + ((kc * 2) ^ ((row & 7) << 4));
      bf16x8 va = *(const bf16x8*)(A  + (size_t)(rowA + row) * K + k0 + kc);
      *(bf16x8*)((char*)As + off) = va;
      bf16x8 vb = *(const bf16x8*)(Bt + (size_t)(colB + row) * K + k0 + kc);
      *(bf16x8*)((char*)Bs + off) = vb;
    }
    __syncthreads();
    bf16x8 af[4][2], bfr[4][2];
    #pragma unroll
    for (int mi = 0; mi < 4; mi++){
      int row = wr + mi * 16 + l16;
      #pragma unroll
      for (int s = 0; s < 2; s++){
        int k = s * 32 + lhi * 8;
        int off = row * 128 + ((k * 2) ^ ((row & 7) << 4));
        af[mi][s] = *(const bf16x8*)((const char*)As + off);
      }
    }
    #pragma unroll
    for (int ni = 0; ni < 4; ni++){
      int row = wc + ni * 16 + l16;
      #pragma unroll
      for (int s = 0; s < 2; s++){
        int k = s * 32 + lhi * 8;
        int off = row * 128 + ((k * 2) ^ ((row & 7) << 4));
        bfr[ni][s] = *(const bf16x8*)((const char*)Bs + off);
      }
    }
    #pragma unroll
    for (int mi = 0; mi < 4; mi++)
      #pragma unroll
      for (int ni = 0; ni < 4; ni++){
        acc[mi][ni] = __builtin_amdgcn_mfma_f32_16x16x32_bf16(af[mi][0], bfr[ni][0], acc[mi][ni], 0, 0, 0);
        acc[mi][ni] = __builtin_amdgcn_mfma_f32_16x16x32_bf16(af[mi][1], bfr[ni][1], acc[mi][ni], 0, 0, 0);
      }
  }
  #pragma unroll
  for (int mi = 0; mi < 4; mi++){
    #pragma unroll
    for (int j = 0; j < 4; j++){
      int r = rowA + wr + mi * 16 + lhi * 4 + j;
      if (BF16OUT){
        unsigned short* Cp = (unsigned short*)Cv + (size_t)r * NN + colB + wc + l16;
        #pragma unroll
        for (int ni = 0; ni < 4; ni++)
          Cp[ni * 16] = f2bf(acc[mi][ni][j]);
      } else {
        float* Cp = (float*)Cv + (size_t)r * NN + colB + wc + l16;
        #pragma unroll
        for (int ni = 0; ni < 4; ni++)
          Cp[ni * 16] = acc[mi][ni][j];
      }
    }
  }
}

// ---------------- el/er from bf16 h: one wave per node, both heads ----------------
template<int D>
__global__ __launch_bounds__(256) void k_elr(const unsigned short* __restrict__ HB,
                                             const float* __restrict__ al,
                                             const float* __restrict__ ar,
                                             float* __restrict__ el, float* __restrict__ er){
  constexpr int ITER = (2*D)/256;
  int wid = threadIdx.x >> 6, lane = threadIdx.x & 63;
  int n = blockIdx.x * 4 + wid;
  const unsigned short* hrow = HB + (size_t)n * (2*D);
  float sl[2] = {0.f, 0.f}, sr[2] = {0.f, 0.f};
  #pragma unroll
  for (int j = 0; j < ITER; j++){
    int base = j*256 + lane*4;
    bf16x4 v = *(const bf16x4*)(hrow + base);
    int hh = (base < D) ? 0 : 1;
    #pragma unroll
    for (int i = 0; i < 4; i++){
      float f = bf2f((unsigned short)v[i]);
      sl[hh] += f * al[base + i];
      sr[hh] += f * ar[base + i];
    }
  }
  #pragma unroll
  for (int o = 32; o; o >>= 1){
    sl[0] += __shfl_xor(sl[0], o); sl[1] += __shfl_xor(sl[1], o);
    sr[0] += __shfl_xor(sr[0], o); sr[1] += __shfl_xor(sr[1], o);
  }
  if (lane < 2){ el[n*2 + lane] = sl[lane]; er[n*2 + lane] = sr[lane]; }
}

// ---------------- attention: one wave per destination node; RB += attn ----------------
// XCD swizzle: contiguous node ranges (whole graphs) per XCD for L2 locality.
template<int D>
__global__ __launch_bounds__(256) void k_attn(const unsigned short* __restrict__ HB,
                                              float* __restrict__ RB,
                                              const float* __restrict__ el,
                                              const float* __restrict__ er,
                                              const int* __restrict__ rowptr,
                                              const int* __restrict__ perm){
  constexpr int ITER = (2*D)/256;
  int wid = threadIdx.x >> 6, lane = threadIdx.x & 63;
  int nb = (blockIdx.x & 7) * (NNODES/4/8) + (blockIdx.x >> 3);   // bijective: 4096 = 8*512
  int n = nb * 4 + wid;
  int r0 = rowptr[n], r1 = rowptr[n+1];
  if (r0 == r1) return;   // no in-edges: output = residual already in RB
  float er0 = er[n*2], er1 = er[n*2+1];
  float mx0 = -1e30f, mx1 = -1e30f;
  for (int e = r0 + lane; e < r1; e += 64){
    int s = perm[e];
    mx0 = fmaxf(mx0, leaky(el[s*2]   + er0, 0.2f));
    mx1 = fmaxf(mx1, leaky(el[s*2+1] + er1, 0.2f));
  }
  #pragma unroll
  for (int o = 32; o; o >>= 1){ mx0 = fmaxf(mx0, __shfl_xor(mx0, o)); mx1 = fmaxf(mx1, __shfl_xor(mx1, o)); }
  float sm0 = 0.0f, sm1 = 0.0f;
  for (int e = r0 + lane; e < r1; e += 64){
    int s = perm[e];
    sm0 += expf(leaky(el[s*2]   + er0, 0.2f) - mx0);
    sm1 += expf(leaky(el[s*2+1] + er1, 0.2f) - mx1);
  }
  #pragma unroll
  for (int o = 32; o; o >>= 1){ sm0 += __shfl_xor(sm0, o); sm1 += __shfl_xor(sm1, o); }
  float inv0 = 1.0f / sm0, inv1 = 1.0f / sm1;
  float acc[ITER][4];
  #pragma unroll
  for (int j = 0; j < ITER; j++)
    #pragma unroll
    for (int i = 0; i < 4; i++) acc[j][i] = 0.0f;
  for (int e = r0; e < r1; ++e){
    int s = perm[e];
    float a0 = expf(leaky(el[s*2]   + er0, 0.2f) - mx0) * inv0;
    float a1 = expf(leaky(el[s*2+1] + er1, 0.2f) - mx1) * inv1;
    const unsigned short* hrow = HB + (size_t)s * (2*D);
    #pragma unroll
    for (int j = 0; j < ITER; j++){
      int base = j*256 + lane*4;
      bf16x4 v = *(const bf16x4*)(hrow + base);
      float a = (base < D) ? a0 : a1;
      #pragma unroll
      for (int i = 0; i < 4; i++)
        acc[j][i] += a * bf2f((unsigned short)v[i]);
    }
  }
  float* rrow = RB + (size_t)n * (2*D);
  #pragma unroll
  for (int j = 0; j < ITER; j++){
    int base = j*256 + lane*4;
    float4 r = *(float4*)(rrow + base);
    r.x += acc[j][0]; r.y += acc[j][1]; r.z += acc[j][2]; r.w += acc[j][3];
    *(float4*)(rrow + base) = r;
  }
}

// ---------------- GraphNorm stats: per-column sums over nodes (columns = 2d) ----------------
__global__ __launch_bounds__(256) void k_stats(const float* __restrict__ R, int nn,
                                               float* __restrict__ gsum, float* __restrict__ gsq){
  __shared__ float rs[256], rq[256];
  int t = threadIdx.x, lane = t & 63, w = t >> 6;
  int nodeb = blockIdx.x * 256;
  for (int ch = 0; ch < nn; ch += 64){
    int col = ch + lane;
    float s = 0.0f, q = 0.0f;
    const float* base = R + (size_t)(nodeb + w*64) * nn + col;
    for (int i = 0; i < 64; i++){ float v = base[(size_t)i * nn]; s += v; q += v*v; }
    rs[t] = s; rq[t] = q; __syncthreads();
    if (t < 64){
      float ss = rs[t] + rs[t+64] + rs[t+128] + rs[t+192];
      float qq = rq[t] + rq[t+64] + rq[t+128] + rq[t+192];
      atomicAdd(&gsum[ch + t], ss);
      atomicAdd(&gsq [ch + t], qq);
    }
    __syncthreads();
  }
}

__global__ void k_finstats(const float* __restrict__ gsum, const float* __restrict__ gsq,
                           const float* __restrict__ alpha,
                           float* __restrict__ mean, float* __restrict__ rstd, int d){
  int t = threadIdx.x;
  if (t >= d) return;
  float s = gsum[t] + gsum[t + d];
  float q = gsq[t]  + gsq[t + d];
  const float M = (float)(2 * NNODES);
  float m   = s / M;
  float msq = q / M;
  float a   = alpha[t];
  float var = msq - a * m * m * (2.0f - a);   // E[(x-am)^2] = E[x^2] - a m^2 (2-a)
  mean[t] = m;
  rstd[t] = rsqrtf(var + 1e-5f);
}

// ---------------- norm apply + leaky + head-mean + graph pooling (fused), bf16 X-out -------
__global__ __launch_bounds__(256) void k_norm_pool(const float* __restrict__ R,
                                                   unsigned short* __restrict__ Xn, // bf16 next-layer input (or null)
                                                   const float* __restrict__ mean,
                                                   const float* __restrict__ rstd,
                                                   const float* __restrict__ gamma,
                                                   const float* __restrict__ beta,
                                                   const float* __restrict__ alpha,
                                                   float* __restrict__ pool, int d, int loff){
  int t = threadIdx.x, lane = t & 63, w = t >> 6;
  int c = blockIdx.y * 64 + lane;
  int nodeb = blockIdx.x * 256 + w * 64;
  int g = blockIdx.x >> 2;                 // 4 node-blocks per graph (1024 nodes/graph)
  float m  = mean[c], rs = rstd[c], ga = gamma[c], be = beta[c];
  float am = alpha[c] * m;
  int nn = 2 * d;
  const float* r0 = R + (size_t)nodeb * nn + c;
  float accp = 0.0f;
  for (int i = 0; i < 64; i++){
    float v0 = r0[(size_t)i * nn];
    float v1 = r0[(size_t)i * nn + d];
    float y0 = ga * (v0 - am) * rs + be; y0 = y0 >= 0.0f ? y0 : 0.01f * y0;
    float y1 = ga * (v1 - am) * rs + be; y1 = y1 >= 0.0f ? y1 : 0.01f * y1;
    if (Xn){
      Xn[(size_t)(nodeb + i) * nn + c]     = f2bf(y0);
      Xn[(size_t)(nodeb + i) * nn + d + c] = f2bf(y1);
    }
    accp += y0 + y1;
  }
  accp *= 0.5f;
  __shared__ float red[256];
  red[t] = accp; __syncthreads();
  if (t < 64){
    float s = red[t] + red[t+64] + red[t+128] + red[t+192];
    atomicAdd(&pool[g * 896 + loff + blockIdx.y * 64 + t], s);
  }
}

__global__ void k_final(const float* __restrict__ pool, const float* __restrict__ counts,
                        float* __restrict__ out){
  int idx = blockIdx.x * 256 + threadIdx.x;
  if (idx >= NGRAPHS * 896) return;
  int g = idx / 896;
  float v = pool[idx] / counts[g];
  out[idx] = v >= 0.0f ? v : 0.01f * v;
}

// ---------------------------------------------------------------------------------------
extern "C" void kernel_launch(void* const* d_in, const int* in_sizes, int n_in,
                              void* d_out, int out_size, void* d_ws, size_t ws_size,
                              hipStream_t stream){
  const float* x0 = (const float*)d_in[0];
  const float *W[3], *AL[3], *AR[3], *RW[3], *GA[3], *BE[3], *ALP[3];
  for (int l = 0; l < 3; l++){
    const int b = 1 + l*7;
    W[l]  = (const float*)d_in[b+0];
    AL[l] = (const float*)d_in[b+1];
    AR[l] = (const float*)d_in[b+2];
    RW[l] = (const float*)d_in[b+3];
    GA[l] = (const float*)d_in[b+4];
    BE[l] = (const float*)d_in[b+5];
    ALP[l]= (const float*)d_in[b+6];
  }
  const int* esrc = (const int*)d_in[22];
  const int* edst = (const int*)d_in[23];
  const int* gid  = (const int*)d_in[24];
  float* out = (float*)d_out;

  char* p = (char*)d_ws;
  auto carve = [&](size_t bytes)->void*{
    void* r = (void*)p; p += (bytes + 255) & ~(size_t)255; return r;
  };
  unsigned short* HB = (unsigned short*)carve((size_t)NNODES * 1024 * 2);  // h bf16 [N, 2d]
  float* RB     = (float*)carve((size_t)NNODES * 1024 * 4);  // r then out [N, 2d] fp32
  unsigned short* X0b = (unsigned short*)carve((size_t)NNODES * 128 * 2);  // bf16 layer-0 input
  unsigned short* XA  = (unsigned short*)carve((size_t)NNODES * 256 * 2);  // bf16 y0
  unsigned short* XB  = (unsigned short*)carve((size_t)NNODES * 512 * 2);  // bf16 y1
  unsigned short* Wt  = (unsigned short*)carve((size_t)1024 * 512 * 2);    // bf16 W^T (max)
  unsigned short* RWt = (unsigned short*)carve((size_t)1024 * 512 * 2);    // bf16 resW^T (max)
  float* el     = (float*)carve((size_t)NNODES * 2 * 4);
  float* er     = (float*)carve((size_t)NNODES * 2 * 4);
  int*   deg    = (int*)  carve((size_t)NNODES * 4);
  int*   rowptr = (int*)  carve((size_t)(NNODES + 1) * 4);
  int*   cursor = (int*)  carve((size_t)NNODES * 4);
  int*   perm   = (int*)  carve((size_t)NEDGES * 4);
  float* stats  = (float*)carve(2048 * 4);                   // gsum[1024] | gsq[1024]
  float* meanb  = (float*)carve(512 * 4);
  float* rstdb  = (float*)carve(512 * 4);
  float* pool   = (float*)carve((size_t)NGRAPHS * 896 * 4);
  float* countsF= (float*)carve((size_t)NGRAPHS * 4);
  (void)ws_size; (void)in_sizes; (void)n_in; (void)out_size;

  hipMemsetAsync(deg, 0, NNODES * 4, stream);
  hipMemsetAsync(pool, 0, NGRAPHS * 896 * 4, stream);
  hipMemsetAsync(countsF, 0, NGRAPHS * 4, stream);

  k_deg    <<<NEDGES/256, 256, 0, stream>>>(edst, deg);
  k_scan   <<<1, 1024, 0, stream>>>(deg, rowptr, cursor);
  k_scatter<<<NEDGES/256, 256, 0, stream>>>(esrc, edst, cursor, perm);
  k_counts <<<NNODES/1024, 256, 0, stream>>>(gid, countsF);
  k_cvt    <<<(NNODES*128/4 + 255)/256, 256, 0, stream>>>(x0, X0b, NNODES*128/4);

  const unsigned short* xin = X0b;
  int loff = 0;
  const int dims[3] = {128, 256, 512};
  for (int l = 0; l < 3; l++){
    int d = dims[l], nn = 2*d;
    dim3 gt(nn/32, d/32);
    k_cvt_t<<<gt, 256, 0, stream>>>(W[l],  Wt,  d, nn);
    k_cvt_t<<<gt, 256, 0, stream>>>(RW[l], RWt, d, nn);
    dim3 gg(nn/128, NNODES/128);
    k_gemm_bf16<true> <<<gg, 256, 0, stream>>>(xin, Wt,  HB, d, nn);
    k_gemm_bf16<false><<<gg, 256, 0, stream>>>(xin, RWt, RB, d, nn);
    if (d == 128){
      k_elr <128><<<NNODES/4, 256, 0, stream>>>(HB, AL[l], AR[l], el, er);
      k_attn<128><<<NNODES/4, 256, 0, stream>>>(HB, RB, el, er, rowptr, perm);
    } else if (d == 256){
      k_elr <256><<<NNODES/4, 256, 0, stream>>>(HB, AL[l], AR[l], el, er);
      k_attn<256><<<NNODES/4, 256, 0, stream>>>(HB, RB, el, er, rowptr, perm);
    } else {
      k_elr <512><<<NNODES/4, 256, 0, stream>>>(HB, AL[l], AR[l], el, er);
      k_attn<512><<<NNODES/4, 256, 0, stream>>>(HB, RB, el, er, rowptr, perm);
    }
    hipMemsetAsync(stats, 0, 2048 * 4, stream);
    k_stats   <<<NNODES/256, 256, 0, stream>>>(RB, nn, stats, stats + 1024);
    k_finstats<<<1, 512, 0, stream>>>(stats, stats + 1024, ALP[l], meanb, rstdb, d);
    unsigned short* xn = (l == 0) ? XA : (l == 1) ? XB : nullptr;
    dim3 gn(NNODES/256, d/64);
    k_norm_pool<<<gn, 256, 0, stream>>>(RB, xn, meanb, rstdb, GA[l], BE[l], ALP[l], pool, d, loff);
    xin = xn; loff += d;
  }
  k_final<<<(NGRAPHS*896 + 255)/256, 256, 0, stream>>>(pool, countsF, out);
}

// Round 6
// 387.732 us; speedup vs baseline: 3.3081x; 1.1316x over previous
//
#include <hip/hip_runtime.h>
#include <math.h>

constexpr int NNODES  = 16384;
constexpr int NEDGES  = 131072;
constexpr int NGRAPHS = 16;

typedef short bf16x8 __attribute__((ext_vector_type(8)));
typedef short bf16x4 __attribute__((ext_vector_type(4)));
typedef float f32x4  __attribute__((ext_vector_type(4)));

__device__ __forceinline__ float leaky(float x, float s){ return x >= 0.0f ? x : s * x; }

__device__ __forceinline__ unsigned short f2bf(float f){
  unsigned u = __builtin_bit_cast(unsigned, f);
  u += 0x7FFFu + ((u >> 16) & 1u);          // round-to-nearest-even
  return (unsigned short)(u >> 16);
}
__device__ __forceinline__ float bf2f(unsigned short u){
  unsigned x = (unsigned)u << 16; return __builtin_bit_cast(float, x);
}

// ---------------- CSR build (edges fixed across layers; build once) ----------------
__global__ void k_deg(const int* __restrict__ dst, int* __restrict__ deg){
  int e = blockIdx.x * 256 + threadIdx.x;
  if (e < NEDGES) atomicAdd(&deg[dst[e]], 1);
}

__global__ __launch_bounds__(1024) void k_scan(const int* __restrict__ deg,
                                               int* __restrict__ rowptr,
                                               int* __restrict__ cursor){
  __shared__ int sums[1024];
  int t = threadIdx.x;
  int loc[16];
  int s = 0;
  #pragma unroll
  for (int i = 0; i < 16; i++){ loc[i] = deg[t*16 + i]; s += loc[i]; }
  sums[t] = s; __syncthreads();
  for (int off = 1; off < 1024; off <<= 1){
    int v = (t >= off) ? sums[t - off] : 0;
    __syncthreads();
    sums[t] += v;
    __syncthreads();
  }
  int base = (t > 0) ? sums[t-1] : 0;
  #pragma unroll
  for (int i = 0; i < 16; i++){
    rowptr[t*16 + i] = base; cursor[t*16 + i] = base; base += loc[i];
  }
  if (t == 1023) rowptr[NNODES] = base;
}

__global__ void k_scatter(const int* __restrict__ src, const int* __restrict__ dst,
                          int* __restrict__ cursor, int* __restrict__ perm){
  int e = blockIdx.x * 256 + threadIdx.x;
  if (e < NEDGES){ int p = atomicAdd(&cursor[dst[e]], 1); perm[p] = src[e]; }
}

// ---- graph-size counts: LDS histogram per block, one global atomic per (block,graph) ----
__global__ __launch_bounds__(256) void k_counts(const int* __restrict__ gid, float* __restrict__ counts){
  __shared__ int h[NGRAPHS];
  int t = threadIdx.x;
  if (t < NGRAPHS) h[t] = 0;
  __syncthreads();
  int base = blockIdx.x * 1024;
  #pragma unroll
  for (int i = 0; i < 4; i++)
    atomicAdd(&h[gid[base + t + i*256]], 1);
  __syncthreads();
  if (t < NGRAPHS && h[t] > 0) atomicAdd(&counts[t], (float)h[t]);
}

// ---------------- fp32 -> bf16 convert (contiguous) ----------------
__global__ void k_cvt(const float* __restrict__ in, unsigned short* __restrict__ out, int n4){
  int i = blockIdx.x * 256 + threadIdx.x;
  if (i >= n4) return;
  float4 v = ((const float4*)in)[i];
  ushort4 o; o.x = f2bf(v.x); o.y = f2bf(v.y); o.z = f2bf(v.z); o.w = f2bf(v.w);
  ((ushort4*)out)[i] = o;
}

// ---------------- fp32 [K][NN] -> bf16 transposed [NN][K] ----------------
__global__ __launch_bounds__(256) void k_cvt_t(const float* __restrict__ W,
                                               unsigned short* __restrict__ Wt,
                                               int K, int NN){
  __shared__ float tile[32][33];
  int n0 = blockIdx.x * 32, k0 = blockIdx.y * 32;
  int tx = threadIdx.x & 31, ty = threadIdx.x >> 5;   // 32 x 8
  #pragma unroll
  for (int i = 0; i < 4; i++)
    tile[ty + i*8][tx] = W[(size_t)(k0 + ty + i*8) * NN + n0 + tx];
  __syncthreads();
  #pragma unroll
  for (int i = 0; i < 4; i++)
    Wt[(size_t)(n0 + ty + i*8) * K + k0 + tx] = f2bf(tile[tx][ty + i*8]);
}

// ---------------- bf16 MFMA GEMM: C[M,NN] = A[M,K] @ Bt[NN,K]^T, 128x128 tile ----------------
// BF16OUT: store C as bf16 (for the attention gather buffer); else fp32.
template<bool BF16OUT>
__global__ __launch_bounds__(256) void k_gemm_bf16(const unsigned short* __restrict__ A,
                                                   const unsigned short* __restrict__ Bt,
                                                   void* __restrict__ Cv, int K, int NN){
  __shared__ unsigned short As[128 * 64];   // [row][k], XOR-swizzled
  __shared__ unsigned short Bs[128 * 64];   // [col][k], XOR-swizzled
  int t = threadIdx.x;
  int lane = t & 63, w = t >> 6;
  int wr = (w >> 1) * 64, wc = (w & 1) * 64;
  int l16 = lane & 15, lhi = lane >> 4;
  int rowA = blockIdx.y * 128;
  int colB = blockIdx.x * 128;
  f32x4 acc[4][4] = {};

  for (int k0 = 0; k0 < K; k0 += 64){
    __syncthreads();
    #pragma unroll
    for (int c = 0; c < 4; c++){
      int chunk = t + c * 256;            // 1024 chunks of 8 bf16
      int row = chunk >> 3, kc = (chunk & 7) * 8;
      int off = row * 128 + ((kc * 2) ^ ((row & 7) << 4));
      bf16x8 va = *(const bf16x8*)(A  + (size_t)(rowA + row) * K + k0 + kc);
      *(bf16x8*)((char*)As + off) = va;
      bf16x8 vb = *(const bf16x8*)(Bt + (size_t)(colB + row) * K + k0 + kc);
      *(bf16x8*)((char*)Bs + off) = vb;
    }
    __syncthreads();
    bf16x8 af[4][2], bfr[4][2];
    #pragma unroll
    for (int mi = 0; mi < 4; mi++){
      int row = wr + mi * 16 + l16;
      #pragma unroll
      for (int s = 0; s < 2; s++){
        int k = s * 32 + lhi * 8;
        int off = row * 128 + ((k * 2) ^ ((row & 7) << 4));
        af[mi][s] = *(const bf16x8*)((const char*)As + off);
      }
    }
    #pragma unroll
    for (int ni = 0; ni < 4; ni++){
      int row = wc + ni * 16 + l16;
      #pragma unroll
      for (int s = 0; s < 2; s++){
        int k = s * 32 + lhi * 8;
        int off = row * 128 + ((k * 2) ^ ((row & 7) << 4));
        bfr[ni][s] = *(const bf16x8*)((const char*)Bs + off);
      }
    }
    #pragma unroll
    for (int mi = 0; mi < 4; mi++)
      #pragma unroll
      for (int ni = 0; ni < 4; ni++){
        acc[mi][ni] = __builtin_amdgcn_mfma_f32_16x16x32_bf16(af[mi][0], bfr[ni][0], acc[mi][ni], 0, 0, 0);
        acc[mi][ni] = __builtin_amdgcn_mfma_f32_16x16x32_bf16(af[mi][1], bfr[ni][1], acc[mi][ni], 0, 0, 0);
      }
  }
  #pragma unroll
  for (int mi = 0; mi < 4; mi++){
    #pragma unroll
    for (int j = 0; j < 4; j++){
      int r = rowA + wr + mi * 16 + lhi * 4 + j;
      if (BF16OUT){
        unsigned short* Cp = (unsigned short*)Cv + (size_t)r * NN + colB + wc + l16;
        #pragma unroll
        for (int ni = 0; ni < 4; ni++)
          Cp[ni * 16] = f2bf(acc[mi][ni][j]);
      } else {
        float* Cp = (float*)Cv + (size_t)r * NN + colB + wc + l16;
        #pragma unroll
        for (int ni = 0; ni < 4; ni++)
          Cp[ni * 16] = acc[mi][ni][j];
      }
    }
  }
}

// ---------------- el/er from bf16 h: one wave per node, both heads ----------------
template<int D>
__global__ __launch_bounds__(256) void k_elr(const unsigned short* __restrict__ HB,
                                             const float* __restrict__ al,
                                             const float* __restrict__ ar,
                                             float* __restrict__ el, float* __restrict__ er){
  constexpr int ITER = (2*D)/256;
  int wid = threadIdx.x >> 6, lane = threadIdx.x & 63;
  int n = blockIdx.x * 4 + wid;
  const unsigned short* hrow = HB + (size_t)n * (2*D);
  float sl[2] = {0.f, 0.f}, sr[2] = {0.f, 0.f};
  #pragma unroll
  for (int j = 0; j < ITER; j++){
    int base = j*256 + lane*4;
    bf16x4 v = *(const bf16x4*)(hrow + base);
    int hh = (base < D) ? 0 : 1;
    #pragma unroll
    for (int i = 0; i < 4; i++){
      float f = bf2f((unsigned short)v[i]);
      sl[hh] += f * al[base + i];
      sr[hh] += f * ar[base + i];
    }
  }
  #pragma unroll
  for (int o = 32; o; o >>= 1){
    sl[0] += __shfl_xor(sl[0], o); sl[1] += __shfl_xor(sl[1], o);
    sr[0] += __shfl_xor(sr[0], o); sr[1] += __shfl_xor(sr[1], o);
  }
  if (lane < 2){ el[n*2 + lane] = sl[lane]; er[n*2 + lane] = sr[lane]; }
}

// ---------------- attention: one wave per destination node; RB += attn ----------------
// XCD swizzle: contiguous node ranges (whole graphs) per XCD for L2 locality.
template<int D>
__global__ __launch_bounds__(256) void k_attn(const unsigned short* __restrict__ HB,
                                              float* __restrict__ RB,
                                              const float* __restrict__ el,
                                              const float* __restrict__ er,
                                              const int* __restrict__ rowptr,
                                              const int* __restrict__ perm){
  constexpr int ITER = (2*D)/256;
  int wid = threadIdx.x >> 6, lane = threadIdx.x & 63;
  int nb = (blockIdx.x & 7) * (NNODES/4/8) + (blockIdx.x >> 3);   // bijective: 4096 = 8*512
  int n = nb * 4 + wid;
  int r0 = rowptr[n], r1 = rowptr[n+1];
  if (r0 == r1) return;   // no in-edges: output = residual already in RB
  float er0 = er[n*2], er1 = er[n*2+1];
  float mx0 = -1e30f, mx1 = -1e30f;
  for (int e = r0 + lane; e < r1; e += 64){
    int s = perm[e];
    mx0 = fmaxf(mx0, leaky(el[s*2]   + er0, 0.2f));
    mx1 = fmaxf(mx1, leaky(el[s*2+1] + er1, 0.2f));
  }
  #pragma unroll
  for (int o = 32; o; o >>= 1){ mx0 = fmaxf(mx0, __shfl_xor(mx0, o)); mx1 = fmaxf(mx1, __shfl_xor(mx1, o)); }
  float sm0 = 0.0f, sm1 = 0.0f;
  for (int e = r0 + lane; e < r1; e += 64){
    int s = perm[e];
    sm0 += expf(leaky(el[s*2]   + er0, 0.2f) - mx0);
    sm1 += expf(leaky(el[s*2+1] + er1, 0.2f) - mx1);
  }
  #pragma unroll
  for (int o = 32; o; o >>= 1){ sm0 += __shfl_xor(sm0, o); sm1 += __shfl_xor(sm1, o); }
  float inv0 = 1.0f / sm0, inv1 = 1.0f / sm1;
  float acc[ITER][4];
  #pragma unroll
  for (int j = 0; j < ITER; j++)
    #pragma unroll
    for (int i = 0; i < 4; i++) acc[j][i] = 0.0f;
  for (int e = r0; e < r1; ++e){
    int s = perm[e];
    float a0 = expf(leaky(el[s*2]   + er0, 0.2f) - mx0) * inv0;
    float a1 = expf(leaky(el[s*2+1] + er1, 0.2f) - mx1) * inv1;
    const unsigned short* hrow = HB + (size_t)s * (2*D);
    #pragma unroll
    for (int j = 0; j < ITER; j++){
      int base = j*256 + lane*4;
      bf16x4 v = *(const bf16x4*)(hrow + base);
      float a = (base < D) ? a0 : a1;
      #pragma unroll
      for (int i = 0; i < 4; i++)
        acc[j][i] += a * bf2f((unsigned short)v[i]);
    }
  }
  float* rrow = RB + (size_t)n * (2*D);
  #pragma unroll
  for (int j = 0; j < ITER; j++){
    int base = j*256 + lane*4;
    float4 r = *(float4*)(rrow + base);
    r.x += acc[j][0]; r.y += acc[j][1]; r.z += acc[j][2]; r.w += acc[j][3];
    *(float4*)(rrow + base) = r;
  }
}

// ------- GraphNorm stats: grid (NNODES/128, nn/256); lane owns 4 cols, float4 loads -------
__global__ __launch_bounds__(256) void k_stats(const float* __restrict__ R, int nn,
                                               float* __restrict__ gsum, float* __restrict__ gsq){
  int t = threadIdx.x, lane = t & 63, w = t >> 6;
  int c = blockIdx.y * 256 + lane * 4;
  const float* base = R + (size_t)(blockIdx.x * 128 + w) * nn + c;
  float4 s = make_float4(0,0,0,0), q = make_float4(0,0,0,0);
  #pragma unroll 4
  for (int i = 0; i < 32; i++){
    float4 v = *(const float4*)(base + (size_t)(i * 4) * nn);
    s.x += v.x; s.y += v.y; s.z += v.z; s.w += v.w;
    q.x += v.x*v.x; q.y += v.y*v.y; q.z += v.z*v.z; q.w += v.w*v.w;
  }
  __shared__ float4 rs[256], rq[256];
  rs[t] = s; rq[t] = q; __syncthreads();
  if (t < 64){
    float4 a = rs[t], b = rs[t+64], c2 = rs[t+128], d2 = rs[t+192];
    float4 e = rq[t], f = rq[t+64], g2 = rq[t+128], h2 = rq[t+192];
    int cc = blockIdx.y * 256 + t * 4;
    atomicAdd(&gsum[cc+0], a.x+b.x+c2.x+d2.x);
    atomicAdd(&gsum[cc+1], a.y+b.y+c2.y+d2.y);
    atomicAdd(&gsum[cc+2], a.z+b.z+c2.z+d2.z);
    atomicAdd(&gsum[cc+3], a.w+b.w+c2.w+d2.w);
    atomicAdd(&gsq [cc+0], e.x+f.x+g2.x+h2.x);
    atomicAdd(&gsq [cc+1], e.y+f.y+g2.y+h2.y);
    atomicAdd(&gsq [cc+2], e.z+f.z+g2.z+h2.z);
    atomicAdd(&gsq [cc+3], e.w+f.w+g2.w+h2.w);
  }
}

__global__ void k_finstats(const float* __restrict__ gsum, const float* __restrict__ gsq,
                           const float* __restrict__ alpha,
                           float* __restrict__ mean, float* __restrict__ rstd, int d){
  int t = threadIdx.x;
  if (t >= d) return;
  float s = gsum[t] + gsum[t + d];
  float q = gsq[t]  + gsq[t + d];
  const float M = (float)(2 * NNODES);
  float m   = s / M;
  float msq = q / M;
  float a   = alpha[t];
  float var = msq - a * m * m * (2.0f - a);   // E[(x-am)^2] = E[x^2] - a m^2 (2-a)
  mean[t] = m;
  rstd[t] = rsqrtf(var + 1e-5f);
}

// -- norm apply + leaky + head-mean pool: grid (NNODES/128, nn/256); float4/ushort4 I/O --
// NOTE: per-channel params are d-length; column c maps to channel c & (d-1).
__global__ __launch_bounds__(256) void k_norm_pool(const float* __restrict__ R,
                                                   unsigned short* __restrict__ Xn, // bf16 next-layer input (or null)
                                                   const float* __restrict__ mean,
                                                   const float* __restrict__ rstd,
                                                   const float* __restrict__ gamma,
                                                   const float* __restrict__ beta,
                                                   const float* __restrict__ alpha,
                                                   float* __restrict__ pool, int d, int loff){
  int t = threadIdx.x, lane = t & 63, w = t >> 6;
  int c = blockIdx.y * 256 + lane * 4;
  int cm = c & (d - 1);                    // channel index (d-periodic), 4-aligned
  int nodeb = blockIdx.x * 128;
  int g = blockIdx.x >> 3;                 // 8 row-blocks per graph (1024 nodes/graph)
  int nn = 2 * d;
  float4 mm = *(const float4*)(mean + cm);
  float4 rr = *(const float4*)(rstd + cm);
  float4 gg = *(const float4*)(gamma + cm);
  float4 bb = *(const float4*)(beta + cm);
  float4 aa = *(const float4*)(alpha + cm);
  float am0 = aa.x*mm.x, am1 = aa.y*mm.y, am2 = aa.z*mm.z, am3 = aa.w*mm.w;
  const float* base = R + (size_t)(nodeb + w) * nn + c;
  unsigned short* xb = Xn ? (Xn + (size_t)(nodeb + w) * nn + c) : nullptr;
  float4 accp = make_float4(0,0,0,0);
  #pragma unroll 4
  for (int i = 0; i < 32; i++){
    float4 v = *(const float4*)(base + (size_t)(i * 4) * nn);
    float y0 = gg.x*(v.x-am0)*rr.x + bb.x; y0 = y0 >= 0.f ? y0 : 0.01f*y0;
    float y1 = gg.y*(v.y-am1)*rr.y + bb.y; y1 = y1 >= 0.f ? y1 : 0.01f*y1;
    float y2 = gg.z*(v.z-am2)*rr.z + bb.z; y2 = y2 >= 0.f ? y2 : 0.01f*y2;
    float y3 = gg.w*(v.w-am3)*rr.w + bb.w; y3 = y3 >= 0.f ? y3 : 0.01f*y3;
    if (xb){
      ushort4 o; o.x = f2bf(y0); o.y = f2bf(y1); o.z = f2bf(y2); o.w = f2bf(y3);
      *(ushort4*)(xb + (size_t)(i * 4) * nn) = o;
    }
    accp.x += y0; accp.y += y1; accp.z += y2; accp.w += y3;
  }
  __shared__ float4 red[256];
  red[t] = accp; __syncthreads();
  if (t < 64){
    float4 a = red[t], b = red[t+64], c2 = red[t+128], d2 = red[t+192];
    int cc = blockIdx.y * 256 + t * 4;
    float* pb = pool + g * 896 + loff;
    atomicAdd(&pb[(cc+0) & (d-1)], 0.5f*(a.x+b.x+c2.x+d2.x));
    atomicAdd(&pb[(cc+1) & (d-1)], 0.5f*(a.y+b.y+c2.y+d2.y));
    atomicAdd(&pb[(cc+2) & (d-1)], 0.5f*(a.z+b.z+c2.z+d2.z));
    atomicAdd(&pb[(cc+3) & (d-1)], 0.5f*(a.w+b.w+c2.w+d2.w));
  }
}

__global__ void k_final(const float* __restrict__ pool, const float* __restrict__ counts,
                        float* __restrict__ out){
  int idx = blockIdx.x * 256 + threadIdx.x;
  if (idx >= NGRAPHS * 896) return;
  int g = idx / 896;
  float v = pool[idx] / counts[g];
  out[idx] = v >= 0.0f ? v : 0.01f * v;
}

// ---------------------------------------------------------------------------------------
extern "C" void kernel_launch(void* const* d_in, const int* in_sizes, int n_in,
                              void* d_out, int out_size, void* d_ws, size_t ws_size,
                              hipStream_t stream){
  const float* x0 = (const float*)d_in[0];
  const float *W[3], *AL[3], *AR[3], *RW[3], *GA[3], *BE[3], *ALP[3];
  for (int l = 0; l < 3; l++){
    const int b = 1 + l*7;
    W[l]  = (const float*)d_in[b+0];
    AL[l] = (const float*)d_in[b+1];
    AR[l] = (const float*)d_in[b+2];
    RW[l] = (const float*)d_in[b+3];
    GA[l] = (const float*)d_in[b+4];
    BE[l] = (const float*)d_in[b+5];
    ALP[l]= (const float*)d_in[b+6];
  }
  const int* esrc = (const int*)d_in[22];
  const int* edst = (const int*)d_in[23];
  const int* gid  = (const int*)d_in[24];
  float* out = (float*)d_out;

  char* p = (char*)d_ws;
  auto carve = [&](size_t bytes)->void*{
    void* r = (void*)p; p += (bytes + 255) & ~(size_t)255; return r;
  };
  unsigned short* HB = (unsigned short*)carve((size_t)NNODES * 1024 * 2);  // h bf16 [N, 2d]
  float* RB     = (float*)carve((size_t)NNODES * 1024 * 4);  // r then out [N, 2d] fp32
  unsigned short* X0b = (unsigned short*)carve((size_t)NNODES * 128 * 2);  // bf16 layer-0 input
  unsigned short* XA  = (unsigned short*)carve((size_t)NNODES * 256 * 2);  // bf16 y0
  unsigned short* XB  = (unsigned short*)carve((size_t)NNODES * 512 * 2);  // bf16 y1
  unsigned short* Wt  = (unsigned short*)carve((size_t)1024 * 512 * 2);    // bf16 W^T (max)
  unsigned short* RWt = (unsigned short*)carve((size_t)1024 * 512 * 2);    // bf16 resW^T (max)
  float* el     = (float*)carve((size_t)NNODES * 2 * 4);
  float* er     = (float*)carve((size_t)NNODES * 2 * 4);
  int*   deg    = (int*)  carve((size_t)NNODES * 4);
  int*   rowptr = (int*)  carve((size_t)(NNODES + 1) * 4);
  int*   cursor = (int*)  carve((size_t)NNODES * 4);
  int*   perm   = (int*)  carve((size_t)NEDGES * 4);
  float* stats  = (float*)carve(2048 * 4);                   // gsum[1024] | gsq[1024]
  float* meanb  = (float*)carve(512 * 4);
  float* rstdb  = (float*)carve(512 * 4);
  float* pool   = (float*)carve((size_t)NGRAPHS * 896 * 4);
  float* countsF= (float*)carve((size_t)NGRAPHS * 4);
  (void)ws_size; (void)in_sizes; (void)n_in; (void)out_size;

  hipMemsetAsync(deg, 0, NNODES * 4, stream);
  hipMemsetAsync(pool, 0, NGRAPHS * 896 * 4, stream);
  hipMemsetAsync(countsF, 0, NGRAPHS * 4, stream);

  k_deg    <<<NEDGES/256, 256, 0, stream>>>(edst, deg);
  k_scan   <<<1, 1024, 0, stream>>>(deg, rowptr, cursor);
  k_scatter<<<NEDGES/256, 256, 0, stream>>>(esrc, edst, cursor, perm);
  k_counts <<<NNODES/1024, 256, 0, stream>>>(gid, countsF);
  k_cvt    <<<(NNODES*128/4 + 255)/256, 256, 0, stream>>>(x0, X0b, NNODES*128/4);

  const unsigned short* xin = X0b;
  int loff = 0;
  const int dims[3] = {128, 256, 512};
  for (int l = 0; l < 3; l++){
    int d = dims[l], nn = 2*d;
    dim3 gt(nn/32, d/32);
    k_cvt_t<<<gt, 256, 0, stream>>>(W[l],  Wt,  d, nn);
    k_cvt_t<<<gt, 256, 0, stream>>>(RW[l], RWt, d, nn);
    dim3 gg(nn/128, NNODES/128);
    k_gemm_bf16<true> <<<gg, 256, 0, stream>>>(xin, Wt,  HB, d, nn);
    k_gemm_bf16<false><<<gg, 256, 0, stream>>>(xin, RWt, RB, d, nn);
    if (d == 128){
      k_elr <128><<<NNODES/4, 256, 0, stream>>>(HB, AL[l], AR[l], el, er);
      k_attn<128><<<NNODES/4, 256, 0, stream>>>(HB, RB, el, er, rowptr, perm);
    } else if (d == 256){
      k_elr <256><<<NNODES/4, 256, 0, stream>>>(HB, AL[l], AR[l], el, er);
      k_attn<256><<<NNODES/4, 256, 0, stream>>>(HB, RB, el, er, rowptr, perm);
    } else {
      k_elr <512><<<NNODES/4, 256, 0, stream>>>(HB, AL[l], AR[l], el, er);
      k_attn<512><<<NNODES/4, 256, 0, stream>>>(HB, RB, el, er, rowptr, perm);
    }
    hipMemsetAsync(stats, 0, 2048 * 4, stream);
    dim3 gs(NNODES/128, nn/256);
    k_stats   <<<gs, 256, 0, stream>>>(RB, nn, stats, stats + 1024);
    k_finstats<<<1, 512, 0, stream>>>(stats, stats + 1024, ALP[l], meanb, rstdb, d);
    unsigned short* xn = (l == 0) ? XA : (l == 1) ? XB : nullptr;
    k_norm_pool<<<gs, 256, 0, stream>>>(RB, xn, meanb, rstdb, GA[l], BE[l], ALP[l], pool, d, loff);
    xin = xn; loff += d;
  }
  k_final<<<(NGRAPHS*896 + 255)/256, 256, 0, stream>>>(pool, countsF, out);
}

// Round 7
// 367.861 us; speedup vs baseline: 3.4868x; 1.0540x over previous
//
#include <hip/hip_runtime.h>
#include <math.h>

constexpr int NNODES  = 16384;
constexpr int NEDGES  = 131072;
constexpr int NGRAPHS = 16;

typedef short bf16x8 __attribute__((ext_vector_type(8)));
typedef short bf16x4 __attribute__((ext_vector_type(4)));
typedef float f32x4  __attribute__((ext_vector_type(4)));

__device__ __forceinline__ float leaky(float x, float s){ return x >= 0.0f ? x : s * x; }

__device__ __forceinline__ unsigned short f2bf(float f){
  unsigned u = __builtin_bit_cast(unsigned, f);
  u += 0x7FFFu + ((u >> 16) & 1u);          // round-to-nearest-even
  return (unsigned short)(u >> 16);
}
__device__ __forceinline__ float bf2f(unsigned short u){
  unsigned x = (unsigned)u << 16; return __builtin_bit_cast(float, x);
}

__device__ __forceinline__ void gload_lds16(const unsigned short* g, unsigned short* l){
  __builtin_amdgcn_global_load_lds((const __attribute__((address_space(1))) void*)g,
                                   (__attribute__((address_space(3))) void*)l, 16, 0, 0);
}

// ---------------- CSR build (edges fixed across layers; build once) ----------------
__global__ void k_deg(const int* __restrict__ dst, int* __restrict__ deg){
  int e = blockIdx.x * 256 + threadIdx.x;
  if (e < NEDGES) atomicAdd(&deg[dst[e]], 1);
}

__global__ __launch_bounds__(1024) void k_scan(const int* __restrict__ deg,
                                               int* __restrict__ rowptr,
                                               int* __restrict__ cursor){
  __shared__ int sums[1024];
  int t = threadIdx.x;
  int loc[16];
  int s = 0;
  #pragma unroll
  for (int i = 0; i < 16; i++){ loc[i] = deg[t*16 + i]; s += loc[i]; }
  sums[t] = s; __syncthreads();
  for (int off = 1; off < 1024; off <<= 1){
    int v = (t >= off) ? sums[t - off] : 0;
    __syncthreads();
    sums[t] += v;
    __syncthreads();
  }
  int base = (t > 0) ? sums[t-1] : 0;
  #pragma unroll
  for (int i = 0; i < 16; i++){
    rowptr[t*16 + i] = base; cursor[t*16 + i] = base; base += loc[i];
  }
  if (t == 1023) rowptr[NNODES] = base;
}

__global__ void k_scatter(const int* __restrict__ src, const int* __restrict__ dst,
                          int* __restrict__ cursor, int* __restrict__ perm){
  int e = blockIdx.x * 256 + threadIdx.x;
  if (e < NEDGES){ int p = atomicAdd(&cursor[dst[e]], 1); perm[p] = src[e]; }
}

// ---- graph-size counts: LDS histogram per block, one global atomic per (block,graph) ----
__global__ __launch_bounds__(256) void k_counts(const int* __restrict__ gid, float* __restrict__ counts){
  __shared__ int h[NGRAPHS];
  int t = threadIdx.x;
  if (t < NGRAPHS) h[t] = 0;
  __syncthreads();
  int base = blockIdx.x * 1024;
  #pragma unroll
  for (int i = 0; i < 4; i++)
    atomicAdd(&h[gid[base + t + i*256]], 1);
  __syncthreads();
  if (t < NGRAPHS && h[t] > 0) atomicAdd(&counts[t], (float)h[t]);
}

// ---------------- fp32 -> bf16 convert (contiguous) ----------------
__global__ void k_cvt(const float* __restrict__ in, unsigned short* __restrict__ out, int n4){
  int i = blockIdx.x * 256 + threadIdx.x;
  if (i >= n4) return;
  float4 v = ((const float4*)in)[i];
  ushort4 o; o.x = f2bf(v.x); o.y = f2bf(v.y); o.z = f2bf(v.z); o.w = f2bf(v.w);
  ((ushort4*)out)[i] = o;
}

// ---------------- fp32 [K][NN] -> bf16 transposed [NN][K] ----------------
__global__ __launch_bounds__(256) void k_cvt_t(const float* __restrict__ W,
                                               unsigned short* __restrict__ Wt,
                                               int K, int NN){
  __shared__ float tile[32][33];
  int n0 = blockIdx.x * 32, k0 = blockIdx.y * 32;
  int tx = threadIdx.x & 31, ty = threadIdx.x >> 5;   // 32 x 8
  #pragma unroll
  for (int i = 0; i < 4; i++)
    tile[ty + i*8][tx] = W[(size_t)(k0 + ty + i*8) * NN + n0 + tx];
  __syncthreads();
  #pragma unroll
  for (int i = 0; i < 4; i++)
    Wt[(size_t)(n0 + ty + i*8) * K + k0 + tx] = f2bf(tile[tx][ty + i*8]);
}

// ------- fused dual bf16 MFMA GEMM: H = A@Wt^T (bf16 out), R = A@RWt^T (fp32 out) -------
// 128x128 tile, BK=64, global_load_lds staging (linear dest, pre-swizzled source),
// XOR-swizzled ds_read fragments, XCD-aware bijective block swizzle.
__global__ __launch_bounds__(256) void k_gemm2(const unsigned short* __restrict__ A,
                                               const unsigned short* __restrict__ Wt,
                                               const unsigned short* __restrict__ RWt,
                                               unsigned short* __restrict__ HB,
                                               float* __restrict__ RB,
                                               int K, int NN){
  __shared__ unsigned short As[128 * 64];
  __shared__ unsigned short Bs[128 * 64];
  int t = threadIdx.x;
  int lane = t & 63, w = t >> 6;
  // XCD swizzle: each XCD gets a contiguous range of row-stripes
  int nx  = gridDim.x;                       // 2*NN/128
  int nwg = nx * gridDim.y;                  // multiple of 8
  int bid = blockIdx.x + blockIdx.y * nx;
  int wg  = (bid & 7) * (nwg >> 3) + (bid >> 3);
  int bx = wg % nx, by = wg / nx;
  int half = nx >> 1;
  bool isW = bx < half;
  const unsigned short* Bt = isW ? Wt : RWt;
  int colB = (isW ? bx : bx - half) * 128;
  int rowA = by * 128;

  int wr = (w >> 1) * 64, wc = (w & 1) * 64;
  int l16 = lane & 15, lhi = lane >> 4;
  // stage: chunk c covers rows [c*8, c*8+8); lane (r8=lane>>3, slot=lane&7).
  // LDS is the XOR-swizzled layout; inverse-swizzle applied to the GLOBAL k-offset:
  // kc_byte = (slot*16) ^ (r8<<4)  (row&7 == r8 since chunks are 8-row aligned)
  int r8  = lane >> 3;
  int kcs = (((lane & 7) * 16) ^ (r8 << 4)) >> 1;   // shorts, lane-constant
  f32x4 acc[4][4] = {};

  for (int k0 = 0; k0 < K; k0 += 64){
    __syncthreads();
    #pragma unroll
    for (int i = 0; i < 4; i++){
      int c = w * 4 + i;
      int row = c * 8 + r8;
      gload_lds16(A  + (size_t)(rowA + row) * K + k0 + kcs, &As[c * 512]);
      gload_lds16(Bt + (size_t)(colB + row) * K + k0 + kcs, &Bs[c * 512]);
    }
    __syncthreads();
    bf16x8 af[4][2], bfr[4][2];
    #pragma unroll
    for (int mi = 0; mi < 4; mi++){
      int row = wr + mi * 16 + l16;
      #pragma unroll
      for (int s = 0; s < 2; s++){
        int k = s * 32 + lhi * 8;
        int off = row * 128 + ((k * 2) ^ ((row & 7) << 4));
        af[mi][s] = *(const bf16x8*)((const char*)As + off);
      }
    }
    #pragma unroll
    for (int ni = 0; ni < 4; ni++){
      int row = wc + ni * 16 + l16;
      #pragma unroll
      for (int s = 0; s < 2; s++){
        int k = s * 32 + lhi * 8;
        int off = row * 128 + ((k * 2) ^ ((row & 7) << 4));
        bfr[ni][s] = *(const bf16x8*)((const char*)Bs + off);
      }
    }
    #pragma unroll
    for (int mi = 0; mi < 4; mi++)
      #pragma unroll
      for (int ni = 0; ni < 4; ni++){
        acc[mi][ni] = __builtin_amdgcn_mfma_f32_16x16x32_bf16(af[mi][0], bfr[ni][0], acc[mi][ni], 0, 0, 0);
        acc[mi][ni] = __builtin_amdgcn_mfma_f32_16x16x32_bf16(af[mi][1], bfr[ni][1], acc[mi][ni], 0, 0, 0);
      }
  }
  #pragma unroll
  for (int mi = 0; mi < 4; mi++){
    #pragma unroll
    for (int j = 0; j < 4; j++){
      int r = rowA + wr + mi * 16 + lhi * 4 + j;
      if (isW){
        unsigned short* Cp = HB + (size_t)r * NN + colB + wc + l16;
        #pragma unroll
        for (int ni = 0; ni < 4; ni++)
          Cp[ni * 16] = f2bf(acc[mi][ni][j]);
      } else {
        float* Cp = RB + (size_t)r * NN + colB + wc + l16;
        #pragma unroll
        for (int ni = 0; ni < 4; ni++)
          Cp[ni * 16] = acc[mi][ni][j];
      }
    }
  }
}

// ---------------- el/er from bf16 h: one wave per node, both heads ----------------
template<int D>
__global__ __launch_bounds__(256) void k_elr(const unsigned short* __restrict__ HB,
                                             const float* __restrict__ al,
                                             const float* __restrict__ ar,
                                             float* __restrict__ el, float* __restrict__ er){
  constexpr int ITER = (2*D)/256;
  int wid = threadIdx.x >> 6, lane = threadIdx.x & 63;
  int n = blockIdx.x * 4 + wid;
  const unsigned short* hrow = HB + (size_t)n * (2*D);
  float sl[2] = {0.f, 0.f}, sr[2] = {0.f, 0.f};
  #pragma unroll
  for (int j = 0; j < ITER; j++){
    int base = j*256 + lane*4;
    bf16x4 v = *(const bf16x4*)(hrow + base);
    int hh = (base < D) ? 0 : 1;
    #pragma unroll
    for (int i = 0; i < 4; i++){
      float f = bf2f((unsigned short)v[i]);
      sl[hh] += f * al[base + i];
      sr[hh] += f * ar[base + i];
    }
  }
  #pragma unroll
  for (int o = 32; o; o >>= 1){
    sl[0] += __shfl_xor(sl[0], o); sl[1] += __shfl_xor(sl[1], o);
    sr[0] += __shfl_xor(sr[0], o); sr[1] += __shfl_xor(sr[1], o);
  }
  if (lane < 2){ el[n*2 + lane] = sl[lane]; er[n*2 + lane] = sr[lane]; }
}

// ---------------- attention: one wave per destination node; RB += attn ----------------
// XCD swizzle: contiguous node ranges (whole graphs) per XCD for L2 locality.
template<int D>
__global__ __launch_bounds__(256) void k_attn(const unsigned short* __restrict__ HB,
                                              float* __restrict__ RB,
                                              const float* __restrict__ el,
                                              const float* __restrict__ er,
                                              const int* __restrict__ rowptr,
                                              const int* __restrict__ perm){
  constexpr int ITER = (2*D)/256;
  int wid = threadIdx.x >> 6, lane = threadIdx.x & 63;
  int nb = (blockIdx.x & 7) * (NNODES/4/8) + (blockIdx.x >> 3);   // bijective: 4096 = 8*512
  int n = nb * 4 + wid;
  int r0 = rowptr[n], r1 = rowptr[n+1];
  if (r0 == r1) return;   // no in-edges: output = residual already in RB
  float er0 = er[n*2], er1 = er[n*2+1];
  float mx0 = -1e30f, mx1 = -1e30f;
  for (int e = r0 + lane; e < r1; e += 64){
    int s = perm[e];
    mx0 = fmaxf(mx0, leaky(el[s*2]   + er0, 0.2f));
    mx1 = fmaxf(mx1, leaky(el[s*2+1] + er1, 0.2f));
  }
  #pragma unroll
  for (int o = 32; o; o >>= 1){ mx0 = fmaxf(mx0, __shfl_xor(mx0, o)); mx1 = fmaxf(mx1, __shfl_xor(mx1, o)); }
  float sm0 = 0.0f, sm1 = 0.0f;
  for (int e = r0 + lane; e < r1; e += 64){
    int s = perm[e];
    sm0 += expf(leaky(el[s*2]   + er0, 0.2f) - mx0);
    sm1 += expf(leaky(el[s*2+1] + er1, 0.2f) - mx1);
  }
  #pragma unroll
  for (int o = 32; o; o >>= 1){ sm0 += __shfl_xor(sm0, o); sm1 += __shfl_xor(sm1, o); }
  float inv0 = 1.0f / sm0, inv1 = 1.0f / sm1;
  float acc[ITER][4];
  #pragma unroll
  for (int j = 0; j < ITER; j++)
    #pragma unroll
    for (int i = 0; i < 4; i++) acc[j][i] = 0.0f;
  for (int e = r0; e < r1; ++e){
    int s = perm[e];
    float a0 = expf(leaky(el[s*2]   + er0, 0.2f) - mx0) * inv0;
    float a1 = expf(leaky(el[s*2+1] + er1, 0.2f) - mx1) * inv1;
    const unsigned short* hrow = HB + (size_t)s * (2*D);
    #pragma unroll
    for (int j = 0; j < ITER; j++){
      int base = j*256 + lane*4;
      bf16x4 v = *(const bf16x4*)(hrow + base);
      float a = (base < D) ? a0 : a1;
      #pragma unroll
      for (int i = 0; i < 4; i++)
        acc[j][i] += a * bf2f((unsigned short)v[i]);
    }
  }
  float* rrow = RB + (size_t)n * (2*D);
  #pragma unroll
  for (int j = 0; j < ITER; j++){
    int base = j*256 + lane*4;
    float4 r = *(float4*)(rrow + base);
    r.x += acc[j][0]; r.y += acc[j][1]; r.z += acc[j][2]; r.w += acc[j][3];
    *(float4*)(rrow + base) = r;
  }
}

// ------- GraphNorm stats: grid (NNODES/128, nn/256); lane owns 4 cols, float4 loads -------
__global__ __launch_bounds__(256) void k_stats(const float* __restrict__ R, int nn,
                                               float* __restrict__ gsum, float* __restrict__ gsq){
  int t = threadIdx.x, lane = t & 63, w = t >> 6;
  int c = blockIdx.y * 256 + lane * 4;
  const float* base = R + (size_t)(blockIdx.x * 128 + w) * nn + c;
  float4 s = make_float4(0,0,0,0), q = make_float4(0,0,0,0);
  #pragma unroll 4
  for (int i = 0; i < 32; i++){
    float4 v = *(const float4*)(base + (size_t)(i * 4) * nn);
    s.x += v.x; s.y += v.y; s.z += v.z; s.w += v.w;
    q.x += v.x*v.x; q.y += v.y*v.y; q.z += v.z*v.z; q.w += v.w*v.w;
  }
  __shared__ float4 rs[256], rq[256];
  rs[t] = s; rq[t] = q; __syncthreads();
  if (t < 64){
    float4 a = rs[t], b = rs[t+64], c2 = rs[t+128], d2 = rs[t+192];
    float4 e = rq[t], f = rq[t+64], g2 = rq[t+128], h2 = rq[t+192];
    int cc = blockIdx.y * 256 + t * 4;
    atomicAdd(&gsum[cc+0], a.x+b.x+c2.x+d2.x);
    atomicAdd(&gsum[cc+1], a.y+b.y+c2.y+d2.y);
    atomicAdd(&gsum[cc+2], a.z+b.z+c2.z+d2.z);
    atomicAdd(&gsum[cc+3], a.w+b.w+c2.w+d2.w);
    atomicAdd(&gsq [cc+0], e.x+f.x+g2.x+h2.x);
    atomicAdd(&gsq [cc+1], e.y+f.y+g2.y+h2.y);
    atomicAdd(&gsq [cc+2], e.z+f.z+g2.z+h2.z);
    atomicAdd(&gsq [cc+3], e.w+f.w+g2.w+h2.w);
  }
}

__global__ void k_finstats(const float* __restrict__ gsum, const float* __restrict__ gsq,
                           const float* __restrict__ alpha,
                           float* __restrict__ mean, float* __restrict__ rstd, int d){
  int t = threadIdx.x;
  if (t >= d) return;
  float s = gsum[t] + gsum[t + d];
  float q = gsq[t]  + gsq[t + d];
  const float M = (float)(2 * NNODES);
  float m   = s / M;
  float msq = q / M;
  float a   = alpha[t];
  float var = msq - a * m * m * (2.0f - a);   // E[(x-am)^2] = E[x^2] - a m^2 (2-a)
  mean[t] = m;
  rstd[t] = rsqrtf(var + 1e-5f);
}

// -- norm apply + leaky + head-mean pool: grid (NNODES/128, nn/256); float4/ushort4 I/O --
// NOTE: per-channel params are d-length; column c maps to channel c & (d-1).
__global__ __launch_bounds__(256) void k_norm_pool(const float* __restrict__ R,
                                                   unsigned short* __restrict__ Xn, // bf16 next-layer input (or null)
                                                   const float* __restrict__ mean,
                                                   const float* __restrict__ rstd,
                                                   const float* __restrict__ gamma,
                                                   const float* __restrict__ beta,
                                                   const float* __restrict__ alpha,
                                                   float* __restrict__ pool, int d, int loff){
  int t = threadIdx.x, lane = t & 63, w = t >> 6;
  int c = blockIdx.y * 256 + lane * 4;
  int cm = c & (d - 1);                    // channel index (d-periodic), 4-aligned
  int nodeb = blockIdx.x * 128;
  int g = blockIdx.x >> 3;                 // 8 row-blocks per graph (1024 nodes/graph)
  int nn = 2 * d;
  float4 mm = *(const float4*)(mean + cm);
  float4 rr = *(const float4*)(rstd + cm);
  float4 gg = *(const float4*)(gamma + cm);
  float4 bb = *(const float4*)(beta + cm);
  float4 aa = *(const float4*)(alpha + cm);
  float am0 = aa.x*mm.x, am1 = aa.y*mm.y, am2 = aa.z*mm.z, am3 = aa.w*mm.w;
  const float* base = R + (size_t)(nodeb + w) * nn + c;
  unsigned short* xb = Xn ? (Xn + (size_t)(nodeb + w) * nn + c) : nullptr;
  float4 accp = make_float4(0,0,0,0);
  #pragma unroll 4
  for (int i = 0; i < 32; i++){
    float4 v = *(const float4*)(base + (size_t)(i * 4) * nn);
    float y0 = gg.x*(v.x-am0)*rr.x + bb.x; y0 = y0 >= 0.f ? y0 : 0.01f*y0;
    float y1 = gg.y*(v.y-am1)*rr.y + bb.y; y1 = y1 >= 0.f ? y1 : 0.01f*y1;
    float y2 = gg.z*(v.z-am2)*rr.z + bb.z; y2 = y2 >= 0.f ? y2 : 0.01f*y2;
    float y3 = gg.w*(v.w-am3)*rr.w + bb.w; y3 = y3 >= 0.f ? y3 : 0.01f*y3;
    if (xb){
      ushort4 o; o.x = f2bf(y0); o.y = f2bf(y1); o.z = f2bf(y2); o.w = f2bf(y3);
      *(ushort4*)(xb + (size_t)(i * 4) * nn) = o;
    }
    accp.x += y0; accp.y += y1; accp.z += y2; accp.w += y3;
  }
  __shared__ float4 red[256];
  red[t] = accp; __syncthreads();
  if (t < 64){
    float4 a = red[t], b = red[t+64], c2 = red[t+128], d2 = red[t+192];
    int cc = blockIdx.y * 256 + t * 4;
    float* pb = pool + g * 896 + loff;
    atomicAdd(&pb[(cc+0) & (d-1)], 0.5f*(a.x+b.x+c2.x+d2.x));
    atomicAdd(&pb[(cc+1) & (d-1)], 0.5f*(a.y+b.y+c2.y+d2.y));
    atomicAdd(&pb[(cc+2) & (d-1)], 0.5f*(a.z+b.z+c2.z+d2.z));
    atomicAdd(&pb[(cc+3) & (d-1)], 0.5f*(a.w+b.w+c2.w+d2.w));
  }
}

__global__ void k_final(const float* __restrict__ pool, const float* __restrict__ counts,
                        float* __restrict__ out){
  int idx = blockIdx.x * 256 + threadIdx.x;
  if (idx >= NGRAPHS * 896) return;
  int g = idx / 896;
  float v = pool[idx] / counts[g];
  out[idx] = v >= 0.0f ? v : 0.01f * v;
}

// ---------------------------------------------------------------------------------------
extern "C" void kernel_launch(void* const* d_in, const int* in_sizes, int n_in,
                              void* d_out, int out_size, void* d_ws, size_t ws_size,
                              hipStream_t stream){
  const float* x0 = (const float*)d_in[0];
  const float *W[3], *AL[3], *AR[3], *RW[3], *GA[3], *BE[3], *ALP[3];
  for (int l = 0; l < 3; l++){
    const int b = 1 + l*7;
    W[l]  = (const float*)d_in[b+0];
    AL[l] = (const float*)d_in[b+1];
    AR[l] = (const float*)d_in[b+2];
    RW[l] = (const float*)d_in[b+3];
    GA[l] = (const float*)d_in[b+4];
    BE[l] = (const float*)d_in[b+5];
    ALP[l]= (const float*)d_in[b+6];
  }
  const int* esrc = (const int*)d_in[22];
  const int* edst = (const int*)d_in[23];
  const int* gid  = (const int*)d_in[24];
  float* out = (float*)d_out;

  char* p = (char*)d_ws;
  auto carve = [&](size_t bytes)->void*{
    void* r = (void*)p; p += (bytes + 255) & ~(size_t)255; return r;
  };
  unsigned short* HB = (unsigned short*)carve((size_t)NNODES * 1024 * 2);  // h bf16 [N, 2d]
  float* RB     = (float*)carve((size_t)NNODES * 1024 * 4);  // r then out [N, 2d] fp32
  unsigned short* X0b = (unsigned short*)carve((size_t)NNODES * 128 * 2);  // bf16 layer-0 input
  unsigned short* XA  = (unsigned short*)carve((size_t)NNODES * 256 * 2);  // bf16 y0
  unsigned short* XB  = (unsigned short*)carve((size_t)NNODES * 512 * 2);  // bf16 y1
  unsigned short* Wt  = (unsigned short*)carve((size_t)1024 * 512 * 2);    // bf16 W^T (max)
  unsigned short* RWt = (unsigned short*)carve((size_t)1024 * 512 * 2);    // bf16 resW^T (max)
  float* el     = (float*)carve((size_t)NNODES * 2 * 4);
  float* er     = (float*)carve((size_t)NNODES * 2 * 4);
  int*   deg    = (int*)  carve((size_t)NNODES * 4);
  int*   rowptr = (int*)  carve((size_t)(NNODES + 1) * 4);
  int*   cursor = (int*)  carve((size_t)NNODES * 4);
  int*   perm   = (int*)  carve((size_t)NEDGES * 4);
  float* stats  = (float*)carve(2048 * 4);                   // gsum[1024] | gsq[1024]
  float* meanb  = (float*)carve(512 * 4);
  float* rstdb  = (float*)carve(512 * 4);
  float* pool   = (float*)carve((size_t)NGRAPHS * 896 * 4);
  float* countsF= (float*)carve((size_t)NGRAPHS * 4);
  (void)ws_size; (void)in_sizes; (void)n_in; (void)out_size;

  hipMemsetAsync(deg, 0, NNODES * 4, stream);
  hipMemsetAsync(pool, 0, NGRAPHS * 896 * 4, stream);
  hipMemsetAsync(countsF, 0, NGRAPHS * 4, stream);

  k_deg    <<<NEDGES/256, 256, 0, stream>>>(edst, deg);
  k_scan   <<<1, 1024, 0, stream>>>(deg, rowptr, cursor);
  k_scatter<<<NEDGES/256, 256, 0, stream>>>(esrc, edst, cursor, perm);
  k_counts <<<NNODES/1024, 256, 0, stream>>>(gid, countsF);
  k_cvt    <<<(NNODES*128/4 + 255)/256, 256, 0, stream>>>(x0, X0b, NNODES*128/4);

  const unsigned short* xin = X0b;
  int loff = 0;
  const int dims[3] = {128, 256, 512};
  for (int l = 0; l < 3; l++){
    int d = dims[l], nn = 2*d;
    dim3 gt(nn/32, d/32);
    k_cvt_t<<<gt, 256, 0, stream>>>(W[l],  Wt,  d, nn);
    k_cvt_t<<<gt, 256, 0, stream>>>(RW[l], RWt, d, nn);
    dim3 gg(2*nn/128, NNODES/128);
    k_gemm2<<<gg, 256, 0, stream>>>(xin, Wt, RWt, HB, RB, d, nn);
    if (d == 128){
      k_elr <128><<<NNODES/4, 256, 0, stream>>>(HB, AL[l], AR[l], el, er);
      k_attn<128><<<NNODES/4, 256, 0, stream>>>(HB, RB, el, er, rowptr, perm);
    } else if (d == 256){
      k_elr <256><<<NNODES/4, 256, 0, stream>>>(HB, AL[l], AR[l], el, er);
      k_attn<256><<<NNODES/4, 256, 0, stream>>>(HB, RB, el, er, rowptr, perm);
    } else {
      k_elr <512><<<NNODES/4, 256, 0, stream>>>(HB, AL[l], AR[l], el, er);
      k_attn<512><<<NNODES/4, 256, 0, stream>>>(HB, RB, el, er, rowptr, perm);
    }
    hipMemsetAsync(stats, 0, 2048 * 4, stream);
    dim3 gs(NNODES/128, nn/256);
    k_stats   <<<gs, 256, 0, stream>>>(RB, nn, stats, stats + 1024);
    k_finstats<<<1, 512, 0, stream>>>(stats, stats + 1024, ALP[l], meanb, rstdb, d);
    unsigned short* xn = (l == 0) ? XA : (l == 1) ? XB : nullptr;
    k_norm_pool<<<gs, 256, 0, stream>>>(RB, xn, meanb, rstdb, GA[l], BE[l], ALP[l], pool, d, loff);
    xin = xn; loff += d;
  }
  k_final<<<(NGRAPHS*896 + 255)/256, 256, 0, stream>>>(pool, countsF, out);
}

// Round 8
// 364.346 us; speedup vs baseline: 3.5204x; 1.0096x over previous
//
#include <hip/hip_runtime.h>
#include <math.h>

constexpr int NNODES  = 16384;
constexpr int NEDGES  = 131072;
constexpr int NGRAPHS = 16;

typedef short bf16x8 __attribute__((ext_vector_type(8)));
typedef short bf16x4 __attribute__((ext_vector_type(4)));
typedef float f32x4  __attribute__((ext_vector_type(4)));

__device__ __forceinline__ float leaky(float x, float s){ return x >= 0.0f ? x : s * x; }

__device__ __forceinline__ unsigned short f2bf(float f){
  unsigned u = __builtin_bit_cast(unsigned, f);
  u += 0x7FFFu + ((u >> 16) & 1u);          // round-to-nearest-even
  return (unsigned short)(u >> 16);
}
__device__ __forceinline__ float bf2f(unsigned short u){
  unsigned x = (unsigned)u << 16; return __builtin_bit_cast(float, x);
}

__device__ __forceinline__ void gload_lds16(const unsigned short* g, unsigned short* l){
  __builtin_amdgcn_global_load_lds((const __attribute__((address_space(1))) void*)g,
                                   (__attribute__((address_space(3))) void*)l, 16, 0, 0);
}

// ---------------- CSR build (edges fixed across layers; build once) ----------------
__global__ void k_deg(const int* __restrict__ dst, int* __restrict__ deg){
  int e = blockIdx.x * 256 + threadIdx.x;
  if (e < NEDGES) atomicAdd(&deg[dst[e]], 1);
}

__global__ __launch_bounds__(1024) void k_scan(const int* __restrict__ deg,
                                               int* __restrict__ rowptr,
                                               int* __restrict__ cursor){
  __shared__ int sums[1024];
  int t = threadIdx.x;
  int loc[16];
  int s = 0;
  #pragma unroll
  for (int i = 0; i < 16; i++){ loc[i] = deg[t*16 + i]; s += loc[i]; }
  sums[t] = s; __syncthreads();
  for (int off = 1; off < 1024; off <<= 1){
    int v = (t >= off) ? sums[t - off] : 0;
    __syncthreads();
    sums[t] += v;
    __syncthreads();
  }
  int base = (t > 0) ? sums[t-1] : 0;
  #pragma unroll
  for (int i = 0; i < 16; i++){
    rowptr[t*16 + i] = base; cursor[t*16 + i] = base; base += loc[i];
  }
  if (t == 1023) rowptr[NNODES] = base;
}

__global__ void k_scatter(const int* __restrict__ src, const int* __restrict__ dst,
                          int* __restrict__ cursor, int* __restrict__ perm){
  int e = blockIdx.x * 256 + threadIdx.x;
  if (e < NEDGES){ int p = atomicAdd(&cursor[dst[e]], 1); perm[p] = src[e]; }
}

// ---- graph-size counts: LDS histogram per block, one global atomic per (block,graph) ----
__global__ __launch_bounds__(256) void k_counts(const int* __restrict__ gid, float* __restrict__ counts){
  __shared__ int h[NGRAPHS];
  int t = threadIdx.x;
  if (t < NGRAPHS) h[t] = 0;
  __syncthreads();
  int base = blockIdx.x * 1024;
  #pragma unroll
  for (int i = 0; i < 4; i++)
    atomicAdd(&h[gid[base + t + i*256]], 1);
  __syncthreads();
  if (t < NGRAPHS && h[t] > 0) atomicAdd(&counts[t], (float)h[t]);
}

// ---------------- fp32 -> bf16 convert (contiguous) ----------------
__global__ void k_cvt(const float* __restrict__ in, unsigned short* __restrict__ out, int n4){
  int i = blockIdx.x * 256 + threadIdx.x;
  if (i >= n4) return;
  float4 v = ((const float4*)in)[i];
  ushort4 o; o.x = f2bf(v.x); o.y = f2bf(v.y); o.z = f2bf(v.z); o.w = f2bf(v.w);
  ((ushort4*)out)[i] = o;
}

// ---------------- fp32 [K][NN] -> bf16 transposed [NN][K] ----------------
__global__ __launch_bounds__(256) void k_cvt_t(const float* __restrict__ W,
                                               unsigned short* __restrict__ Wt,
                                               int K, int NN){
  __shared__ float tile[32][33];
  int n0 = blockIdx.x * 32, k0 = blockIdx.y * 32;
  int tx = threadIdx.x & 31, ty = threadIdx.x >> 5;   // 32 x 8
  #pragma unroll
  for (int i = 0; i < 4; i++)
    tile[ty + i*8][tx] = W[(size_t)(k0 + ty + i*8) * NN + n0 + tx];
  __syncthreads();
  #pragma unroll
  for (int i = 0; i < 4; i++)
    Wt[(size_t)(n0 + ty + i*8) * K + k0 + tx] = f2bf(tile[tx][ty + i*8]);
}

// ------- fused dual bf16 MFMA GEMM: H = A@Wt^T (bf16 out), R = A@RWt^T (fp32 out) -------
// 128x128 tile, BK=64, 2-phase double-buffered LDS (T3 minimal recipe):
// issue next-tile global_load_lds BEFORE computing current tile; ONE __syncthreads
// per K-step (its implicit vmcnt(0)+lgkmcnt(0) drain is the recipe's sync point).
__global__ __launch_bounds__(256) void k_gemm2(const unsigned short* __restrict__ A,
                                               const unsigned short* __restrict__ Wt,
                                               const unsigned short* __restrict__ RWt,
                                               unsigned short* __restrict__ HB,
                                               float* __restrict__ RB,
                                               int K, int NN){
  __shared__ unsigned short As[2][128 * 64];
  __shared__ unsigned short Bs[2][128 * 64];
  int t = threadIdx.x;
  int lane = t & 63, w = t >> 6;
  // XCD swizzle: each XCD gets a contiguous range of row-stripes
  int nx  = gridDim.x;                       // 2*NN/128
  int nwg = nx * gridDim.y;                  // multiple of 8
  int bid = blockIdx.x + blockIdx.y * nx;
  int wg  = (bid & 7) * (nwg >> 3) + (bid >> 3);
  int bx = wg % nx, by = wg / nx;
  int half = nx >> 1;
  bool isW = bx < half;
  const unsigned short* Bt = isW ? Wt : RWt;
  int colB = (isW ? bx : bx - half) * 128;
  int rowA = by * 128;

  int wr = (w >> 1) * 64, wc = (w & 1) * 64;
  int l16 = lane & 15, lhi = lane >> 4;
  // stage: chunk c covers rows [c*8, c*8+8); lane (r8=lane>>3, slot=lane&7).
  // LDS is the XOR-swizzled layout; inverse-swizzle applied to the GLOBAL k-offset:
  // kc_byte = (slot*16) ^ (r8<<4)  (row&7 == r8 since chunks are 8-row aligned)
  int r8  = lane >> 3;
  int kcs = (((lane & 7) * 16) ^ (r8 << 4)) >> 1;   // shorts, lane-constant
  f32x4 acc[4][4] = {};

  const unsigned short* Ap = A  + (size_t)(rowA) * K + kcs;
  const unsigned short* Bp = Bt + (size_t)(colB) * K + kcs;

  int nt = K >> 6;
  // prologue: stage tile 0 into buf 0
  #pragma unroll
  for (int i = 0; i < 4; i++){
    int c = w * 4 + i;
    int row = c * 8 + r8;
    gload_lds16(Ap + (size_t)row * K, &As[0][c * 512]);
    gload_lds16(Bp + (size_t)row * K, &Bs[0][c * 512]);
  }
  __syncthreads();

  int cur = 0;
  for (int tI = 0; tI < nt; tI++){
    // issue next-tile stage into the other buffer (overlaps with compute below)
    if (tI + 1 < nt){
      int k0n = (tI + 1) << 6;
      #pragma unroll
      for (int i = 0; i < 4; i++){
        int c = w * 4 + i;
        int row = c * 8 + r8;
        gload_lds16(Ap + (size_t)row * K + k0n, &As[cur ^ 1][c * 512]);
        gload_lds16(Bp + (size_t)row * K + k0n, &Bs[cur ^ 1][c * 512]);
      }
    }
    // compute current tile
    bf16x8 af[4][2], bfr[4][2];
    #pragma unroll
    for (int mi = 0; mi < 4; mi++){
      int row = wr + mi * 16 + l16;
      #pragma unroll
      for (int s = 0; s < 2; s++){
        int k = s * 32 + lhi * 8;
        int off = row * 128 + ((k * 2) ^ ((row & 7) << 4));
        af[mi][s] = *(const bf16x8*)((const char*)As[cur] + off);
      }
    }
    #pragma unroll
    for (int ni = 0; ni < 4; ni++){
      int row = wc + ni * 16 + l16;
      #pragma unroll
      for (int s = 0; s < 2; s++){
        int k = s * 32 + lhi * 8;
        int off = row * 128 + ((k * 2) ^ ((row & 7) << 4));
        bfr[ni][s] = *(const bf16x8*)((const char*)Bs[cur] + off);
      }
    }
    #pragma unroll
    for (int mi = 0; mi < 4; mi++)
      #pragma unroll
      for (int ni = 0; ni < 4; ni++){
        acc[mi][ni] = __builtin_amdgcn_mfma_f32_16x16x32_bf16(af[mi][0], bfr[ni][0], acc[mi][ni], 0, 0, 0);
        acc[mi][ni] = __builtin_amdgcn_mfma_f32_16x16x32_bf16(af[mi][1], bfr[ni][1], acc[mi][ni], 0, 0, 0);
      }
    // one barrier per K-step: drains stage (next buf ready) + all waves done reading cur
    __syncthreads();
    cur ^= 1;
  }

  #pragma unroll
  for (int mi = 0; mi < 4; mi++){
    #pragma unroll
    for (int j = 0; j < 4; j++){
      int r = rowA + wr + mi * 16 + lhi * 4 + j;
      if (isW){
        unsigned short* Cp = HB + (size_t)r * NN + colB + wc + l16;
        #pragma unroll
        for (int ni = 0; ni < 4; ni++)
          Cp[ni * 16] = f2bf(acc[mi][ni][j]);
      } else {
        float* Cp = RB + (size_t)r * NN + colB + wc + l16;
        #pragma unroll
        for (int ni = 0; ni < 4; ni++)
          Cp[ni * 16] = acc[mi][ni][j];
      }
    }
  }
}

// ---------------- el/er from bf16 h: one wave per node, both heads ----------------
template<int D>
__global__ __launch_bounds__(256) void k_elr(const unsigned short* __restrict__ HB,
                                             const float* __restrict__ al,
                                             const float* __restrict__ ar,
                                             float* __restrict__ el, float* __restrict__ er){
  constexpr int ITER = (2*D)/256;
  int wid = threadIdx.x >> 6, lane = threadIdx.x & 63;
  int n = blockIdx.x * 4 + wid;
  const unsigned short* hrow = HB + (size_t)n * (2*D);
  float sl[2] = {0.f, 0.f}, sr[2] = {0.f, 0.f};
  #pragma unroll
  for (int j = 0; j < ITER; j++){
    int base = j*256 + lane*4;
    bf16x4 v = *(const bf16x4*)(hrow + base);
    int hh = (base < D) ? 0 : 1;
    #pragma unroll
    for (int i = 0; i < 4; i++){
      float f = bf2f((unsigned short)v[i]);
      sl[hh] += f * al[base + i];
      sr[hh] += f * ar[base + i];
    }
  }
  #pragma unroll
  for (int o = 32; o; o >>= 1){
    sl[0] += __shfl_xor(sl[0], o); sl[1] += __shfl_xor(sl[1], o);
    sr[0] += __shfl_xor(sr[0], o); sr[1] += __shfl_xor(sr[1], o);
  }
  if (lane < 2){ el[n*2 + lane] = sl[lane]; er[n*2 + lane] = sr[lane]; }
}

// ---------------- attention: one wave per destination node; RB += attn ----------------
// XCD swizzle: contiguous node ranges (whole graphs) per XCD for L2 locality.
template<int D>
__global__ __launch_bounds__(256) void k_attn(const unsigned short* __restrict__ HB,
                                              float* __restrict__ RB,
                                              const float* __restrict__ el,
                                              const float* __restrict__ er,
                                              const int* __restrict__ rowptr,
                                              const int* __restrict__ perm){
  constexpr int ITER = (2*D)/256;
  int wid = threadIdx.x >> 6, lane = threadIdx.x & 63;
  int nb = (blockIdx.x & 7) * (NNODES/4/8) + (blockIdx.x >> 3);   // bijective: 4096 = 8*512
  int n = nb * 4 + wid;
  int r0 = rowptr[n], r1 = rowptr[n+1];
  if (r0 == r1) return;   // no in-edges: output = residual already in RB
  float er0 = er[n*2], er1 = er[n*2+1];
  float mx0 = -1e30f, mx1 = -1e30f;
  for (int e = r0 + lane; e < r1; e += 64){
    int s = perm[e];
    mx0 = fmaxf(mx0, leaky(el[s*2]   + er0, 0.2f));
    mx1 = fmaxf(mx1, leaky(el[s*2+1] + er1, 0.2f));
  }
  #pragma unroll
  for (int o = 32; o; o >>= 1){ mx0 = fmaxf(mx0, __shfl_xor(mx0, o)); mx1 = fmaxf(mx1, __shfl_xor(mx1, o)); }
  float sm0 = 0.0f, sm1 = 0.0f;
  for (int e = r0 + lane; e < r1; e += 64){
    int s = perm[e];
    sm0 += expf(leaky(el[s*2]   + er0, 0.2f) - mx0);
    sm1 += expf(leaky(el[s*2+1] + er1, 0.2f) - mx1);
  }
  #pragma unroll
  for (int o = 32; o; o >>= 1){ sm0 += __shfl_xor(sm0, o); sm1 += __shfl_xor(sm1, o); }
  float inv0 = 1.0f / sm0, inv1 = 1.0f / sm1;
  float acc[ITER][4];
  #pragma unroll
  for (int j = 0; j < ITER; j++)
    #pragma unroll
    for (int i = 0; i < 4; i++) acc[j][i] = 0.0f;
  for (int e = r0; e < r1; ++e){
    int s = perm[e];
    float a0 = expf(leaky(el[s*2]   + er0, 0.2f) - mx0) * inv0;
    float a1 = expf(leaky(el[s*2+1] + er1, 0.2f) - mx1) * inv1;
    const unsigned short* hrow = HB + (size_t)s * (2*D);
    #pragma unroll
    for (int j = 0; j < ITER; j++){
      int base = j*256 + lane*4;
      bf16x4 v = *(const bf16x4*)(hrow + base);
      float a = (base < D) ? a0 : a1;
      #pragma unroll
      for (int i = 0; i < 4; i++)
        acc[j][i] += a * bf2f((unsigned short)v[i]);
    }
  }
  float* rrow = RB + (size_t)n * (2*D);
  #pragma unroll
  for (int j = 0; j < ITER; j++){
    int base = j*256 + lane*4;
    float4 r = *(float4*)(rrow + base);
    r.x += acc[j][0]; r.y += acc[j][1]; r.z += acc[j][2]; r.w += acc[j][3];
    *(float4*)(rrow + base) = r;
  }
}

// ------- GraphNorm stats: grid (NNODES/128, nn/256); lane owns 4 cols, float4 loads -------
__global__ __launch_bounds__(256) void k_stats(const float* __restrict__ R, int nn,
                                               float* __restrict__ gsum, float* __restrict__ gsq){
  int t = threadIdx.x, lane = t & 63, w = t >> 6;
  int c = blockIdx.y * 256 + lane * 4;
  const float* base = R + (size_t)(blockIdx.x * 128 + w) * nn + c;
  float4 s = make_float4(0,0,0,0), q = make_float4(0,0,0,0);
  #pragma unroll 4
  for (int i = 0; i < 32; i++){
    float4 v = *(const float4*)(base + (size_t)(i * 4) * nn);
    s.x += v.x; s.y += v.y; s.z += v.z; s.w += v.w;
    q.x += v.x*v.x; q.y += v.y*v.y; q.z += v.z*v.z; q.w += v.w*v.w;
  }
  __shared__ float4 rs[256], rq[256];
  rs[t] = s; rq[t] = q; __syncthreads();
  if (t < 64){
    float4 a = rs[t], b = rs[t+64], c2 = rs[t+128], d2 = rs[t+192];
    float4 e = rq[t], f = rq[t+64], g2 = rq[t+128], h2 = rq[t+192];
    int cc = blockIdx.y * 256 + t * 4;
    atomicAdd(&gsum[cc+0], a.x+b.x+c2.x+d2.x);
    atomicAdd(&gsum[cc+1], a.y+b.y+c2.y+d2.y);
    atomicAdd(&gsum[cc+2], a.z+b.z+c2.z+d2.z);
    atomicAdd(&gsum[cc+3], a.w+b.w+c2.w+d2.w);
    atomicAdd(&gsq [cc+0], e.x+f.x+g2.x+h2.x);
    atomicAdd(&gsq [cc+1], e.y+f.y+g2.y+h2.y);
    atomicAdd(&gsq [cc+2], e.z+f.z+g2.z+h2.z);
    atomicAdd(&gsq [cc+3], e.w+f.w+g2.w+h2.w);
  }
}

__global__ void k_finstats(const float* __restrict__ gsum, const float* __restrict__ gsq,
                           const float* __restrict__ alpha,
                           float* __restrict__ mean, float* __restrict__ rstd, int d){
  int t = threadIdx.x;
  if (t >= d) return;
  float s = gsum[t] + gsum[t + d];
  float q = gsq[t]  + gsq[t + d];
  const float M = (float)(2 * NNODES);
  float m   = s / M;
  float msq = q / M;
  float a   = alpha[t];
  float var = msq - a * m * m * (2.0f - a);   // E[(x-am)^2] = E[x^2] - a m^2 (2-a)
  mean[t] = m;
  rstd[t] = rsqrtf(var + 1e-5f);
}

// -- norm apply + leaky + head-mean pool: grid (NNODES/128, nn/256); float4/ushort4 I/O --
// NOTE: per-channel params are d-length; column c maps to channel c & (d-1).
__global__ __launch_bounds__(256) void k_norm_pool(const float* __restrict__ R,
                                                   unsigned short* __restrict__ Xn, // bf16 next-layer input (or null)
                                                   const float* __restrict__ mean,
                                                   const float* __restrict__ rstd,
                                                   const float* __restrict__ gamma,
                                                   const float* __restrict__ beta,
                                                   const float* __restrict__ alpha,
                                                   float* __restrict__ pool, int d, int loff){
  int t = threadIdx.x, lane = t & 63, w = t >> 6;
  int c = blockIdx.y * 256 + lane * 4;
  int cm = c & (d - 1);                    // channel index (d-periodic), 4-aligned
  int nodeb = blockIdx.x * 128;
  int g = blockIdx.x >> 3;                 // 8 row-blocks per graph (1024 nodes/graph)
  int nn = 2 * d;
  float4 mm = *(const float4*)(mean + cm);
  float4 rr = *(const float4*)(rstd + cm);
  float4 gg = *(const float4*)(gamma + cm);
  float4 bb = *(const float4*)(beta + cm);
  float4 aa = *(const float4*)(alpha + cm);
  float am0 = aa.x*mm.x, am1 = aa.y*mm.y, am2 = aa.z*mm.z, am3 = aa.w*mm.w;
  const float* base = R + (size_t)(nodeb + w) * nn + c;
  unsigned short* xb = Xn ? (Xn + (size_t)(nodeb + w) * nn + c) : nullptr;
  float4 accp = make_float4(0,0,0,0);
  #pragma unroll 4
  for (int i = 0; i < 32; i++){
    float4 v = *(const float4*)(base + (size_t)(i * 4) * nn);
    float y0 = gg.x*(v.x-am0)*rr.x + bb.x; y0 = y0 >= 0.f ? y0 : 0.01f*y0;
    float y1 = gg.y*(v.y-am1)*rr.y + bb.y; y1 = y1 >= 0.f ? y1 : 0.01f*y1;
    float y2 = gg.z*(v.z-am2)*rr.z + bb.z; y2 = y2 >= 0.f ? y2 : 0.01f*y2;
    float y3 = gg.w*(v.w-am3)*rr.w + bb.w; y3 = y3 >= 0.f ? y3 : 0.01f*y3;
    if (xb){
      ushort4 o; o.x = f2bf(y0); o.y = f2bf(y1); o.z = f2bf(y2); o.w = f2bf(y3);
      *(ushort4*)(xb + (size_t)(i * 4) * nn) = o;
    }
    accp.x += y0; accp.y += y1; accp.z += y2; accp.w += y3;
  }
  __shared__ float4 red[256];
  red[t] = accp; __syncthreads();
  if (t < 64){
    float4 a = red[t], b = red[t+64], c2 = red[t+128], d2 = red[t+192];
    int cc = blockIdx.y * 256 + t * 4;
    float* pb = pool + g * 896 + loff;
    atomicAdd(&pb[(cc+0) & (d-1)], 0.5f*(a.x+b.x+c2.x+d2.x));
    atomicAdd(&pb[(cc+1) & (d-1)], 0.5f*(a.y+b.y+c2.y+d2.y));
    atomicAdd(&pb[(cc+2) & (d-1)], 0.5f*(a.z+b.z+c2.z+d2.z));
    atomicAdd(&pb[(cc+3) & (d-1)], 0.5f*(a.w+b.w+c2.w+d2.w));
  }
}

__global__ void k_final(const float* __restrict__ pool, const float* __restrict__ counts,
                        float* __restrict__ out){
  int idx = blockIdx.x * 256 + threadIdx.x;
  if (idx >= NGRAPHS * 896) return;
  int g = idx / 896;
  float v = pool[idx] / counts[g];
  out[idx] = v >= 0.0f ? v : 0.01f * v;
}

// ---------------------------------------------------------------------------------------
extern "C" void kernel_launch(void* const* d_in, const int* in_sizes, int n_in,
                              void* d_out, int out_size, void* d_ws, size_t ws_size,
                              hipStream_t stream){
  const float* x0 = (const float*)d_in[0];
  const float *W[3], *AL[3], *AR[3], *RW[3], *GA[3], *BE[3], *ALP[3];
  for (int l = 0; l < 3; l++){
    const int b = 1 + l*7;
    W[l]  = (const float*)d_in[b+0];
    AL[l] = (const float*)d_in[b+1];
    AR[l] = (const float*)d_in[b+2];
    RW[l] = (const float*)d_in[b+3];
    GA[l] = (const float*)d_in[b+4];
    BE[l] = (const float*)d_in[b+5];
    ALP[l]= (const float*)d_in[b+6];
  }
  const int* esrc = (const int*)d_in[22];
  const int* edst = (const int*)d_in[23];
  const int* gid  = (const int*)d_in[24];
  float* out = (float*)d_out;

  char* p = (char*)d_ws;
  auto carve = [&](size_t bytes)->void*{
    void* r = (void*)p; p += (bytes + 255) & ~(size_t)255; return r;
  };
  unsigned short* HB = (unsigned short*)carve((size_t)NNODES * 1024 * 2);  // h bf16 [N, 2d]
  float* RB     = (float*)carve((size_t)NNODES * 1024 * 4);  // r then out [N, 2d] fp32
  unsigned short* X0b = (unsigned short*)carve((size_t)NNODES * 128 * 2);  // bf16 layer-0 input
  unsigned short* XA  = (unsigned short*)carve((size_t)NNODES * 256 * 2);  // bf16 y0
  unsigned short* XB  = (unsigned short*)carve((size_t)NNODES * 512 * 2);  // bf16 y1
  unsigned short* Wt  = (unsigned short*)carve((size_t)1024 * 512 * 2);    // bf16 W^T (max)
  unsigned short* RWt = (unsigned short*)carve((size_t)1024 * 512 * 2);    // bf16 resW^T (max)
  float* el     = (float*)carve((size_t)NNODES * 2 * 4);
  float* er     = (float*)carve((size_t)NNODES * 2 * 4);
  int*   deg    = (int*)  carve((size_t)NNODES * 4);
  int*   rowptr = (int*)  carve((size_t)(NNODES + 1) * 4);
  int*   cursor = (int*)  carve((size_t)NNODES * 4);
  int*   perm   = (int*)  carve((size_t)NEDGES * 4);
  float* stats  = (float*)carve(2048 * 4);                   // gsum[1024] | gsq[1024]
  float* meanb  = (float*)carve(512 * 4);
  float* rstdb  = (float*)carve(512 * 4);
  float* pool   = (float*)carve((size_t)NGRAPHS * 896 * 4);
  float* countsF= (float*)carve((size_t)NGRAPHS * 4);
  (void)ws_size; (void)in_sizes; (void)n_in; (void)out_size;

  hipMemsetAsync(deg, 0, NNODES * 4, stream);
  hipMemsetAsync(pool, 0, NGRAPHS * 896 * 4, stream);
  hipMemsetAsync(countsF, 0, NGRAPHS * 4, stream);

  k_deg    <<<NEDGES/256, 256, 0, stream>>>(edst, deg);
  k_scan   <<<1, 1024, 0, stream>>>(deg, rowptr, cursor);
  k_scatter<<<NEDGES/256, 256, 0, stream>>>(esrc, edst, cursor, perm);
  k_counts <<<NNODES/1024, 256, 0, stream>>>(gid, countsF);
  k_cvt    <<<(NNODES*128/4 + 255)/256, 256, 0, stream>>>(x0, X0b, NNODES*128/4);

  const unsigned short* xin = X0b;
  int loff = 0;
  const int dims[3] = {128, 256, 512};
  for (int l = 0; l < 3; l++){
    int d = dims[l], nn = 2*d;
    dim3 gt(nn/32, d/32);
    k_cvt_t<<<gt, 256, 0, stream>>>(W[l],  Wt,  d, nn);
    k_cvt_t<<<gt, 256, 0, stream>>>(RW[l], RWt, d, nn);
    dim3 gg(2*nn/128, NNODES/128);
    k_gemm2<<<gg, 256, 0, stream>>>(xin, Wt, RWt, HB, RB, d, nn);
    if (d == 128){
      k_elr <128><<<NNODES/4, 256, 0, stream>>>(HB, AL[l], AR[l], el, er);
      k_attn<128><<<NNODES/4, 256, 0, stream>>>(HB, RB, el, er, rowptr, perm);
    } else if (d == 256){
      k_elr <256><<<NNODES/4, 256, 0, stream>>>(HB, AL[l], AR[l], el, er);
      k_attn<256><<<NNODES/4, 256, 0, stream>>>(HB, RB, el, er, rowptr, perm);
    } else {
      k_elr <512><<<NNODES/4, 256, 0, stream>>>(HB, AL[l], AR[l], el, er);
      k_attn<512><<<NNODES/4, 256, 0, stream>>>(HB, RB, el, er, rowptr, perm);
    }
    hipMemsetAsync(stats, 0, 2048 * 4, stream);
    dim3 gs(NNODES/128, nn/256);
    k_stats   <<<gs, 256, 0, stream>>>(RB, nn, stats, stats + 1024);
    k_finstats<<<1, 512, 0, stream>>>(stats, stats + 1024, ALP[l], meanb, rstdb, d);
    unsigned short* xn = (l == 0) ? XA : (l == 1) ? XB : nullptr;
    k_norm_pool<<<gs, 256, 0, stream>>>(RB, xn, meanb, rstdb, GA[l], BE[l], ALP[l], pool, d, loff);
    xin = xn; loff += d;
  }
  k_final<<<(NGRAPHS*896 + 255)/256, 256, 0, stream>>>(pool, countsF, out);
}